// Round 11
// baseline (208.470 us; speedup 1.0000x reference)
//
#include <hip/hip_runtime.h>
#include <hip/hip_bf16.h>

// CompositionalKoopmanOperators: B=32,N=64,ATTR=4,STATE=8,REL=4,GDIM=32,NF=128,pstep=2
// Round 11: 3-kernel pipeline. Node updates (pp+LN+relu, recv/send terms,
// predictor) are per-row, so they run as tails of the 2048-block edge kernels
// (per-row GEMV, transposed bf16 weights, coalesced). aggb never materialized.
//   k_node(128) -> k_edge_fused(2048, +pn0 tail) -> k_prop_edge2(2048, +pn1+pred tail)

#define ROWS 2048   // B*N
typedef unsigned short u16;
typedef unsigned int u32;
typedef __attribute__((ext_vector_type(8))) short bf16x8;   // 8 bf16 = 4 VGPR
typedef __attribute__((ext_vector_type(4))) float f32x4;

__device__ __forceinline__ float bsu(u16 u) { return __uint_as_float(((u32)u) << 16); }
__device__ __forceinline__ u16 f2b(float f) {
    u32 u = __float_as_uint(f);
    u32 r = (u + 0x7fffu + ((u >> 16) & 1u)) >> 16;   // RNE
    return (u16)r;
}
__device__ __forceinline__ u32 pk2(float a, float b) {
    __hip_bfloat162 h = __float22bfloat162_rn(float2{a, b});
    union { __hip_bfloat162 h; u32 u; } c; c.h = h; return c.u;
}
__device__ __forceinline__ bf16x8 ldcvt8(const float* __restrict__ p) {
    float4 a = *(const float4*)p;
    float4 b = *(const float4*)(p + 4);
    union { u32 u[4]; bf16x8 v; } x;
    x.u[0] = pk2(a.x, a.y); x.u[1] = pk2(a.z, a.w);
    x.u[2] = pk2(b.x, b.y); x.u[3] = pk2(b.z, b.w);
    return x.v;
}

// ---------------- k_node: weight prep + L0 + 3 MFMA GEMMs + recvS0/sendS0 ----------
__global__ __launch_bounds__(256)
void k_node(const float* __restrict__ attrs, const float* __restrict__ states,
            const float* __restrict__ oe_w0, const float* __restrict__ oe_b0,
            const float* __restrict__ oe_w1, const float* __restrict__ oe_b1,
            const float* __restrict__ re_w0, const float* __restrict__ re_b0,
            const float* __restrict__ rp_w,  const float* __restrict__ rp_b,
            const float* __restrict__ re_w1, const float* __restrict__ pp_w,
            const float* __restrict__ pr_w0, const float* __restrict__ pr_w1,
            u16* __restrict__ re_w1b, u16* __restrict__ web, u16* __restrict__ pp_wT,
            u16* __restrict__ wrecvT, u16* __restrict__ wsendT,
            u16* __restrict__ pr_w0T, u16* __restrict__ pr_w1T, u16* __restrict__ wsumb,
            u16* __restrict__ objb, float* __restrict__ nr, float* __restrict__ ns,
            float* __restrict__ recvT, float* __restrict__ sendT,
            float* __restrict__ recvS0, float* __restrict__ sendS0)
{
    const int r0 = blockIdx.x * 16;
    const int t = threadIdx.x;
    __shared__ float xs[16][12];
    __shared__ float w0s[1536];
    __shared__ float rw0s[2560];
    __shared__ __align__(16) u16 hb[16 * 136];
    __shared__ __align__(16) u16 ob[16 * 136];

    // ---- distributed weight prep (118784 values); GEMV weights transposed ----
    {
        int gid = blockIdx.x * 256 + t;
        for (int i = gid; i < 118784; i += 32768) {
            int idx = i;
            if (idx < 16384) { re_w1b[idx] = f2b(re_w1[idx]); continue; }
            idx -= 16384;
            if (idx < 16384) { web[idx] = f2b(rp_w[(idx >> 7) * 384 + (idx & 127)]); continue; }
            idx -= 16384;
            if (idx < 32768) { int k = idx >> 7, o = idx & 127;
                pp_wT[idx] = f2b(pp_w[o * 256 + k]); continue; }
            idx -= 32768;
            if (idx < 16384) { int k = idx >> 7, o = idx & 127;
                wrecvT[idx] = f2b(rp_w[o * 384 + 128 + k]); continue; }
            idx -= 16384;
            if (idx < 16384) { int k = idx >> 7, o = idx & 127;
                wsendT[idx] = f2b(rp_w[o * 384 + 256 + k]); continue; }
            idx -= 16384;
            if (idx < 16384) { int k = idx >> 7, o = idx & 127;
                pr_w0T[idx] = f2b(pr_w0[o * 128 + k]); continue; }
            idx -= 16384;
            { int k = idx >> 5, o = idx & 31; pr_w1T[idx] = f2b(pr_w1[o * 128 + k]); }
        }
    }
    if (blockIdx.x == 0 && t < 128) {
        float s = 0.f;
        for (int o = 0; o < 128; o++) s += bsu(f2b(rp_w[o * 384 + t]));
        wsumb[t] = f2b(s);
    }

    if (t < 192) { int row = t / 12, c = t - row * 12;
        xs[row][c] = (c < 4) ? attrs[(r0 + row) * 4 + c] : states[(r0 + row) * 8 + (c - 4)]; }
    for (int i = t; i < 1536; i += 256) w0s[i] = oe_w0[i];
    for (int i = t; i < 2560; i += 256) rw0s[i] = re_w0[i];
    __syncthreads();

    for (int e = t; e < 2048; e += 256) {
        int row = e >> 7, o = e & 127;
        float h = oe_b0[o];
#pragma unroll
        for (int k = 0; k < 12; k++) h += w0s[o * 12 + k] * xs[row][k];
        hb[row * 136 + o] = f2b(fmaxf(h, 0.f));
        float s0 = 0.f, a0 = 0.f, a1 = 0.f;
#pragma unroll
        for (int k = 0; k < 8; k++) s0 += rw0s[o * 20 + 4 + k] * xs[row][4 + k];
#pragma unroll
        for (int k = 0; k < 4; k++) {
            a0 += rw0s[o * 20 + 12 + k] * xs[row][k];
            a1 += rw0s[o * 20 + 16 + k] * xs[row][k];
        }
        nr[(r0 + row) * 128 + o] = s0 + a0 + re_b0[o];
        ns[(r0 + row) * 128 + o] = a1 - s0;
    }
    __syncthreads();

    const int wave = t >> 6, lane = t & 63, tx = lane & 15, quad = lane >> 4;

    bf16x8 afr[4];
#pragma unroll
    for (int kk = 0; kk < 4; kk++) afr[kk] = *(const bf16x8*)&hb[tx * 136 + kk * 32 + quad * 8];
    f32x4 acc[2]; acc[0] = (f32x4){0.f,0.f,0.f,0.f}; acc[1] = acc[0];
#pragma unroll
    for (int ot = 0; ot < 2; ot++) {
        int o = (wave * 2 + ot) * 16 + tx;
#pragma unroll
        for (int kk = 0; kk < 4; kk++) {
            bf16x8 bfr = ldcvt8(&oe_w1[o * 128 + kk * 32 + quad * 8]);
            acc[ot] = __builtin_amdgcn_mfma_f32_16x16x32_bf16(afr[kk], bfr, acc[ot], 0, 0, 0);
        }
    }
#pragma unroll
    for (int ot = 0; ot < 2; ot++) {
        int o = (wave * 2 + ot) * 16 + tx;
        float bia = oe_b1[o];
#pragma unroll
        for (int r = 0; r < 4; r++)
            ob[(quad * 4 + r) * 136 + o] = f2b(fmaxf(acc[ot][r] + bia, 0.f));
    }
    __syncthreads();
    { int m = t >> 4, c = t & 15;
      *(uint4*)&objb[(r0 + m) * 128 + c * 8] = *(const uint4*)&ob[m * 136 + c * 8]; }

#pragma unroll
    for (int kk = 0; kk < 4; kk++) afr[kk] = *(const bf16x8*)&ob[tx * 136 + kk * 32 + quad * 8];
    f32x4 ar[2], an[2];
    ar[0] = (f32x4){0.f,0.f,0.f,0.f}; ar[1] = ar[0]; an[0] = ar[0]; an[1] = ar[0];
#pragma unroll
    for (int ot = 0; ot < 2; ot++) {
        int o = (wave * 2 + ot) * 16 + tx;
#pragma unroll
        for (int kk = 0; kk < 4; kk++) {
            bf16x8 br = ldcvt8(&rp_w[o * 384 + 128 + kk * 32 + quad * 8]);
            ar[ot] = __builtin_amdgcn_mfma_f32_16x16x32_bf16(afr[kk], br, ar[ot], 0, 0, 0);
            bf16x8 bs = ldcvt8(&rp_w[o * 384 + 256 + kk * 32 + quad * 8]);
            an[ot] = __builtin_amdgcn_mfma_f32_16x16x32_bf16(afr[kk], bs, an[ot], 0, 0, 0);
        }
    }
    float rbv[2] = { rp_b[(wave * 2 + 0) * 16 + tx], rp_b[(wave * 2 + 1) * 16 + tx] };
#pragma unroll
    for (int ot = 0; ot < 2; ot++) {
        int o = (wave * 2 + ot) * 16 + tx;
#pragma unroll
        for (int r = 0; r < 4; r++) {
            recvT[(r0 + quad * 4 + r) * 128 + o] = ar[ot][r] + rbv[ot];
            sendT[(r0 + quad * 4 + r) * 128 + o] = an[ot][r];
        }
    }
    __syncthreads();
    float* fr  = (float*)hb;   // [16][68]
    float* fs2 = (float*)ob;   // [16][68]
#pragma unroll
    for (int r = 0; r < 4; r++) {
        int row = quad * 4 + r;
        fr[row * 68 + wave * 16 + tx]  = (ar[0][r] + rbv[0]) + (ar[1][r] + rbv[1]);
        fs2[row * 68 + wave * 16 + tx] = an[0][r] + an[1][r];
    }
    __syncthreads();
    if (t < 32) {
        int p = t >> 4, row = t & 15;
        const float* src = p ? fs2 : fr;
        float s = 0.f;
#pragma unroll
        for (int k = 0; k < 64; k++) s += src[row * 68 + k];
        (p ? sendS0 : recvS0)[r0 + row] = s;
    }
}

// ---------------- k_edge_fused: GEMM1 -> GEMM2/E -> step-0 LN/agg -> pn0 tail ---------
__global__ __launch_bounds__(256)
void k_edge_fused(const float* __restrict__ rel_attrs,
                  const float* __restrict__ re_w0, const u16* __restrict__ re_w1b,
                  const u16* __restrict__ web, const u16* __restrict__ wsumb,
                  const float* __restrict__ re_b1,
                  const float* __restrict__ rp_lnw, const float* __restrict__ rp_lnb,
                  const float* __restrict__ nr, const float* __restrict__ ns,
                  const float* __restrict__ recvT, const float* __restrict__ sendT,
                  const float* __restrict__ recvS0, const float* __restrict__ sendS0,
                  const u16* __restrict__ objb,
                  const u16* __restrict__ pp_wT, const float* __restrict__ pp_b,
                  const float* __restrict__ pp_lnw, const float* __restrict__ pp_lnb,
                  const u16* __restrict__ wrecvT, const u16* __restrict__ wsendT,
                  const float* __restrict__ rp_b,
                  u16* __restrict__ Ebuf, float* __restrict__ rowsumE,
                  u16* __restrict__ obj1b, float* __restrict__ recvT1,
                  float* __restrict__ sendT1,
                  float* __restrict__ recvS1v, float* __restrict__ sendS1v)
{
    const int blkg = blockIdx.x;    // b*64 + i
    const int b = blkg >> 6;
    const int t = threadIdx.x;
    __shared__ __align__(16) u16 hsb[64 * 144];     // h0, then relE (18432 B)
    __shared__ float lnws[128], lnbs[128];
    __shared__ float redQ[256];
    __shared__ float xv[256];
    __shared__ float part[256];
    __shared__ float red2[8];

    if (t < 128) { lnws[t] = rp_lnw[t]; lnbs[t] = rp_lnb[t]; }

    // phase 1: h0
    {
        const int o0 = (t & 15) * 8;
        const int jb = t >> 4;
        float4 nr0 = *(const float4*)&nr[blkg * 128 + o0];
        float4 nr1 = *(const float4*)&nr[blkg * 128 + o0 + 4];
        float4 wreg[8];
#pragma unroll
        for (int k = 0; k < 8; k++) wreg[k] = *(const float4*)&re_w0[(o0 + k) * 20];
#pragma unroll
        for (int it = 0; it < 4; it++) {
            int j = jb + it * 16;
            float4 ra = *(const float4*)&rel_attrs[((size_t)blkg * 64 + j) * 4];
            const float* nsp = &ns[(b * 64 + j) * 128 + o0];
            float4 na = *(const float4*)nsp;
            float4 nb = *(const float4*)(nsp + 4);
            float v[8];
            v[0] = nr0.x + na.x; v[1] = nr0.y + na.y; v[2] = nr0.z + na.z; v[3] = nr0.w + na.w;
            v[4] = nr1.x + nb.x; v[5] = nr1.y + nb.y; v[6] = nr1.z + nb.z; v[7] = nr1.w + nb.w;
#pragma unroll
            for (int k = 0; k < 8; k++) {
                v[k] += wreg[k].x * ra.x + wreg[k].y * ra.y + wreg[k].z * ra.z + wreg[k].w * ra.w;
                v[k] = fmaxf(v[k], 0.f);
            }
            union { u32 u[4]; uint4 q; } p;
            p.u[0] = pk2(v[0], v[1]); p.u[1] = pk2(v[2], v[3]);
            p.u[2] = pk2(v[4], v[5]); p.u[3] = pk2(v[6], v[7]);
            *(uint4*)&hsb[j * 144 + o0] = p.q;
        }
    }

    const int w = t >> 6, lane = t & 63, tx = lane & 15, quad = lane >> 4;
    const int ob = w * 32;

    bf16x8 b1[2][4];
#pragma unroll
    for (int ot = 0; ot < 2; ot++)
#pragma unroll
        for (int kk = 0; kk < 4; kk++)
            b1[ot][kk] = *(const bf16x8*)&re_w1b[(ob + ot * 16 + tx) * 128 + kk * 32 + quad * 8];
    __syncthreads();

    // GEMM1
    f32x4 acc[4][2];
#pragma unroll
    for (int jt = 0; jt < 4; jt++) { acc[jt][0] = (f32x4){0.f,0.f,0.f,0.f}; acc[jt][1] = acc[jt][0]; }
#pragma unroll
    for (int jt = 0; jt < 4; jt++) {
        bf16x8 afr[4];
#pragma unroll
        for (int kk = 0; kk < 4; kk++)
            afr[kk] = *(const bf16x8*)&hsb[(jt * 16 + tx) * 144 + kk * 32 + quad * 8];
#pragma unroll
        for (int ot = 0; ot < 2; ot++)
#pragma unroll
            for (int kk = 0; kk < 4; kk++)
                acc[jt][ot] = __builtin_amdgcn_mfma_f32_16x16x32_bf16(afr[kk], b1[ot][kk], acc[jt][ot], 0, 0, 0);
    }
    __syncthreads();

    // epilogue1 -> relE
    {
        float bia0 = re_b1[ob + tx], bia1 = re_b1[ob + 16 + tx];
#pragma unroll
        for (int jt = 0; jt < 4; jt++)
#pragma unroll
            for (int r = 0; r < 4; r++) {
                int j = jt * 16 + quad * 4 + r;
                hsb[j * 144 + ob + tx]      = f2b(fmaxf(acc[jt][0][r] + bia0, 0.f));
                hsb[j * 144 + ob + 16 + tx] = f2b(fmaxf(acc[jt][1][r] + bia1, 0.f));
            }
    }
    bf16x8 b2[2][4];
#pragma unroll
    for (int ot = 0; ot < 2; ot++)
#pragma unroll
        for (int kk = 0; kk < 4; kk++)
            b2[ot][kk] = *(const bf16x8*)&web[(ob + ot * 16 + tx) * 128 + kk * 32 + quad * 8];
    bf16x8 bws[4];
#pragma unroll
    for (int kk = 0; kk < 4; kk++)
        bws[kk] = *(const bf16x8*)&wsumb[kk * 32 + quad * 8];
    __syncthreads();

    // GEMM2 + rowsum MFMA
    f32x4 acc2[4][2], acc_ws[4];
#pragma unroll
    for (int jt = 0; jt < 4; jt++) {
        acc2[jt][0] = (f32x4){0.f,0.f,0.f,0.f}; acc2[jt][1] = acc2[jt][0];
        acc_ws[jt] = acc2[jt][0];
    }
#pragma unroll
    for (int jt = 0; jt < 4; jt++) {
        bf16x8 afr[4];
#pragma unroll
        for (int kk = 0; kk < 4; kk++)
            afr[kk] = *(const bf16x8*)&hsb[(jt * 16 + tx) * 144 + kk * 32 + quad * 8];
#pragma unroll
        for (int ot = 0; ot < 2; ot++)
#pragma unroll
            for (int kk = 0; kk < 4; kk++)
                acc2[jt][ot] = __builtin_amdgcn_mfma_f32_16x16x32_bf16(afr[kk], b2[ot][kk], acc2[jt][ot], 0, 0, 0);
#pragma unroll
        for (int kk = 0; kk < 4; kk++)
            acc_ws[jt] = __builtin_amdgcn_mfma_f32_16x16x32_bf16(afr[kk], bws[kk], acc_ws[jt], 0, 0, 0);
    }

    // store E + rowsumE
#pragma unroll
    for (int jt = 0; jt < 4; jt++)
#pragma unroll
        for (int ot = 0; ot < 2; ot++) {
            uint2 ev;
            ev.x = pk2(acc2[jt][ot][0], acc2[jt][ot][1]);
            ev.y = pk2(acc2[jt][ot][2], acc2[jt][ot][3]);
            *(uint2*)(Ebuf + ((size_t)((blkg * 4 + jt) * 8 + (2 * w + ot)) * 64 + lane) * 4) = ev;
        }
    if (w == 0 && tx == 0) {
#pragma unroll
        for (int jt = 0; jt < 4; jt++)
            *(f32x4*)&rowsumE[(size_t)blkg * 64 + jt * 16 + quad * 4] = acc_ws[jt];
    }

    // y = E + recvT0 + sendT0
    {
        float rv0 = recvT[blkg * 128 + ob + tx];
        float rv1 = recvT[blkg * 128 + ob + 16 + tx];
#pragma unroll
        for (int jt = 0; jt < 4; jt++)
#pragma unroll
            for (int r = 0; r < 4; r++) {
                int j = b * 64 + jt * 16 + quad * 4 + r;
                acc2[jt][0][r] += rv0 + sendT[j * 128 + ob + tx];
                acc2[jt][1][r] += rv1 + sendT[j * 128 + ob + 16 + tx];
            }
    }

    // q partials
#pragma unroll
    for (int jt = 0; jt < 4; jt++) {
        float q4[4];
#pragma unroll
        for (int r = 0; r < 4; r++) {
            float a0 = acc2[jt][0][r], a1 = acc2[jt][1][r];
            q4[r] = a0 * a0 + a1 * a1;
        }
#pragma unroll
        for (int m = 1; m < 16; m <<= 1)
#pragma unroll
            for (int r = 0; r < 4; r++) q4[r] += __shfl_xor(q4[r], m, 64);
        if (tx == 0)
#pragma unroll
            for (int r = 0; r < 4; r++) redQ[w * 64 + jt * 16 + quad * 4 + r] = q4[r];
    }
    __syncthreads();

    // normalize + relu + per-col agg -> xv[128..255]
    {
        float recvSi = recvS0[blkg];
        float lw0 = lnws[ob + tx], lb0 = lnbs[ob + tx];
        float lw1 = lnws[ob + 16 + tx], lb1 = lnbs[ob + 16 + tx];
        float ag0 = 0.f, ag1 = 0.f;
#pragma unroll
        for (int jt = 0; jt < 4; jt++) {
            f32x4 ssf = *(const f32x4*)&sendS0[b * 64 + jt * 16 + quad * 4];
#pragma unroll
            for (int r = 0; r < 4; r++) {
                int row = jt * 16 + quad * 4 + r;
                float qq = redQ[row] + redQ[64 + row] + redQ[128 + row] + redQ[192 + row];
                float mu = (acc_ws[jt][r] + recvSi + ssf[r]) * (1.f / 128.f);
                float rsd = rsqrtf(qq * (1.f / 128.f) - mu * mu + 1e-5f);
                float z0 = (acc2[jt][0][r] - mu) * rsd * lw0 + lb0;
                float z1 = (acc2[jt][1][r] - mu) * rsd * lw1 + lb1;
                ag0 += fmaxf(z0, 0.f);
                ag1 += fmaxf(z1, 0.f);
            }
        }
        ag0 += __shfl_xor(ag0, 16, 64); ag0 += __shfl_xor(ag0, 32, 64);
        ag1 += __shfl_xor(ag1, 16, 64); ag1 += __shfl_xor(ag1, 32, 64);
        if (quad == 0) {
            xv[128 + ob + tx]      = ag0;
            xv[128 + ob + 16 + tx] = ag1;
        }
    }
    if (t < 128) xv[t] = bsu(objb[blkg * 128 + t]);
    __syncthreads();

    // ---- pn0 tail (row blkg): pp GEMV (k-split over 256 threads) ----
    {
        int o = t & 127, h = t >> 7;
        const u16* wp = pp_wT + h * 128 * 128 + o;
        const float* xp = xv + h * 128;
        float p = 0.f;
#pragma unroll 16
        for (int kk = 0; kk < 128; kk++) p += xp[kk] * bsu(wp[kk * 128]);
        part[t] = p;
    }
    __syncthreads();
    float val = 0.f;
    if (t < 128) {
        val = part[t] + part[128 + t] + pp_b[t];
        float s = val, q = val * val;
#pragma unroll
        for (int m = 1; m < 64; m <<= 1) { s += __shfl_xor(s, m, 64); q += __shfl_xor(q, m, 64); }
        if (lane == 0) { red2[w * 2] = s; red2[w * 2 + 1] = q; }
    }
    __syncthreads();
    if (t < 128) {
        float ss = red2[0] + red2[2], qq = red2[1] + red2[3];
        float mu = ss * (1.f / 128.f);
        float rsd = rsqrtf(qq * (1.f / 128.f) - mu * mu + 1e-5f);
        float z = (val - mu) * rsd * pp_lnw[t] + pp_lnb[t];
        float o1 = fmaxf(z, 0.f);
        obj1b[blkg * 128 + t] = f2b(o1);
        xv[t] = o1;
    }
    __syncthreads();
    // recvT1 (waves 0-1) / sendT1 (waves 2-3)
    {
        int o = t & 127;
        const u16* wT = (t < 128) ? wrecvT : wsendT;
        float a = 0.f;
#pragma unroll 16
        for (int k = 0; k < 128; k++) a += xv[k] * bsu(wT[k * 128 + o]);
        if (t < 128) a += rp_b[o];
        float s = a;
#pragma unroll
        for (int m = 1; m < 64; m <<= 1) s += __shfl_xor(s, m, 64);
        if (lane == 0) red2[4 + w] = s;
        if (t < 128) recvT1[blkg * 128 + o] = a;
        else         sendT1[blkg * 128 + o] = a;
    }
    __syncthreads();
    if (t == 0) recvS1v[blkg] = red2[4] + red2[5];
    else if (t == 128) sendS1v[blkg] = red2[6] + red2[7];
}

// ---------------- k_prop_edge2: step-1 LN/agg + pn1 + predictor tail ----------------
__global__ __launch_bounds__(256)
void k_prop_edge2(const u16* __restrict__ Ebuf, const float* __restrict__ rowsumE,
                  const float* __restrict__ rp_lnw, const float* __restrict__ rp_lnb,
                  const float* __restrict__ recvT1, const float* __restrict__ sendT1,
                  const float* __restrict__ recvS1v, const float* __restrict__ sendS1v,
                  const u16* __restrict__ obj1b,
                  const u16* __restrict__ pp_wT, const float* __restrict__ pp_b,
                  const float* __restrict__ pp_lnw, const float* __restrict__ pp_lnb,
                  const u16* __restrict__ pr_w0T, const float* __restrict__ pr_b0,
                  const u16* __restrict__ pr_w1T, const float* __restrict__ pr_b1,
                  float* __restrict__ out)
{
    const int blk = blockIdx.x;   // b*64 + i
    const int b = blk >> 6;
    const int t = threadIdx.x;
    __shared__ float scr[16 * 132];
    __shared__ float lnws[128], lnbs[128];
    __shared__ float xv[256];
    __shared__ float part[256];
    __shared__ float red2[8];
    if (t < 128) { lnws[t] = rp_lnw[t]; lnbs[t] = rp_lnb[t]; }
    __syncthreads();

    const int wave = t >> 6, lane = t & 63, tx = lane & 15, quad = lane >> 4;
    const int tid = blk * 4 + wave;
    const int jrow = wave * 16 + quad * 4;

    float y[8][4];
#pragma unroll
    for (int oo = 0; oo < 8; oo++) {
        uint2 ev = *(const uint2*)(Ebuf + ((size_t)(tid * 8 + oo) * 64 + lane) * 4);
        const int o = oo * 16 + tx;
        float rv = recvT1[blk * 128 + o];
        float e0 = bsu((u16)(ev.x & 0xffff)), e1 = bsu((u16)(ev.x >> 16));
        float e2 = bsu((u16)(ev.y & 0xffff)), e3 = bsu((u16)(ev.y >> 16));
        y[oo][0] = e0 + rv + sendT1[(b * 64 + jrow + 0) * 128 + o];
        y[oo][1] = e1 + rv + sendT1[(b * 64 + jrow + 1) * 128 + o];
        y[oo][2] = e2 + rv + sendT1[(b * 64 + jrow + 2) * 128 + o];
        y[oo][3] = e3 + rv + sendT1[(b * 64 + jrow + 3) * 128 + o];
    }
    float q[4];
#pragma unroll
    for (int r = 0; r < 4; r++) {
        q[r] = 0.f;
#pragma unroll
        for (int oo = 0; oo < 8; oo++) q[r] += y[oo][r] * y[oo][r];
    }
#pragma unroll
    for (int m = 1; m < 16; m <<= 1)
#pragma unroll
        for (int r = 0; r < 4; r++) q[r] += __shfl_xor(q[r], m, 64);

    float recvSi = recvS1v[blk];
    f32x4 rse = *(const f32x4*)&rowsumE[(size_t)blk * 64 + jrow];
    f32x4 ssf = *(const f32x4*)&sendS1v[b * 64 + jrow];
    float mu[4], rs[4];
#pragma unroll
    for (int r = 0; r < 4; r++) {
        mu[r] = (rse[r] + recvSi + ssf[r]) * (1.f / 128.f);
        rs[r] = rsqrtf(q[r] * (1.f / 128.f) - mu[r] * mu[r] + 1e-5f);
    }
    float pa[8];
#pragma unroll
    for (int oo = 0; oo < 8; oo++) {
        const int o = oo * 16 + tx;
        float lw = lnws[o], lb = lnbs[o];
        float p = 0.f;
#pragma unroll
        for (int r = 0; r < 4; r++) {
            float z = (y[oo][r] - mu[r]) * rs[r] * lw + lb;
            p += fmaxf(z, 0.f);
        }
        pa[oo] = p;
    }
    const int grp = wave * 4 + quad;
#pragma unroll
    for (int oo = 0; oo < 8; oo++) scr[grp * 132 + oo * 16 + tx] = pa[oo];
    if (t < 128) xv[t] = bsu(obj1b[blk * 128 + t]);
    __syncthreads();
    if (t < 128) {
        float sum = 0.f;
#pragma unroll
        for (int gg = 0; gg < 16; gg++) sum += scr[gg * 132 + t];
        xv[128 + t] = sum;     // agg1 stays in LDS
    }
    __syncthreads();

    // ---- pn1 tail: pp GEMV (k-split) ----
    {
        int o = t & 127, h = t >> 7;
        const u16* wp = pp_wT + h * 128 * 128 + o;
        const float* xp = xv + h * 128;
        float p = 0.f;
#pragma unroll 16
        for (int kk = 0; kk < 128; kk++) p += xp[kk] * bsu(wp[kk * 128]);
        part[t] = p;
    }
    __syncthreads();
    float val = 0.f;
    if (t < 128) {
        val = part[t] + part[128 + t] + pp_b[t];
        float s = val, qq2 = val * val;
#pragma unroll
        for (int m = 1; m < 64; m <<= 1) { s += __shfl_xor(s, m, 64); qq2 += __shfl_xor(qq2, m, 64); }
        if (lane == 0) { red2[wave * 2] = s; red2[wave * 2 + 1] = qq2; }
    }
    __syncthreads();
    if (t < 128) {
        float ss = red2[0] + red2[2], qq = red2[1] + red2[3];
        float muv = ss * (1.f / 128.f);
        float rsd = rsqrtf(qq * (1.f / 128.f) - muv * muv + 1e-5f);
        float z = (val - muv) * rsd * pp_lnw[t] + pp_lnb[t];
        xv[t] = fmaxf(z, 0.f);     // obj2
    }
    __syncthreads();

    // ---- predictor L0: h = relu(obj2 @ pr_w0^T + b0) (k-split) ----
    {
        int o = t & 127, h = t >> 7;
        const u16* wp = pr_w0T + h * 64 * 128 + o;   // k = h*64 + kk (128 k over 2 halves of 64)
        const float* xp = xv + h * 64;
        float p = 0.f;
#pragma unroll 16
        for (int kk = 0; kk < 64; kk++) p += xp[kk] * bsu(wp[kk * 128]);
        part[t] = p;
    }
    __syncthreads();
    if (t < 128) {
        float hv = fmaxf(part[t] + part[128 + t] + pr_b0[t], 0.f);
        xv[128 + t] = hv;
    }
    __syncthreads();

    // ---- predictor L1 (GDIM=32) + tanh ----
    if (t < 128) {
        int o = t & 31, kq = t >> 5;
        const u16* wp = pr_w1T + kq * 32 * 32 + o;
        const float* hp = xv + 128 + kq * 32;
        float p = 0.f;
#pragma unroll
        for (int kk = 0; kk < 32; kk++) p += hp[kk] * bsu(wp[kk * 32]);
        part[t] = p;
    }
    __syncthreads();
    if (t < 32) {
        float a = part[t] + part[32 + t] + part[64 + t] + part[96 + t] + pr_b1[t];
        out[blk * 32 + t] = tanhf(a);
    }
}

extern "C" void kernel_launch(void* const* d_in, const int* in_sizes, int n_in,
                              void* d_out, int out_size, void* d_ws, size_t ws_size,
                              hipStream_t stream)
{
    const float* attrs    = (const float*)d_in[0];
    const float* states   = (const float*)d_in[1];
    const float* rel_attrs= (const float*)d_in[3];
    const float* oe_w0 = (const float*)d_in[4];
    const float* oe_b0 = (const float*)d_in[5];
    const float* oe_w1 = (const float*)d_in[6];
    const float* oe_b1 = (const float*)d_in[7];
    const float* re_w0 = (const float*)d_in[8];
    const float* re_b0 = (const float*)d_in[9];
    const float* re_w1 = (const float*)d_in[10];
    const float* re_b1 = (const float*)d_in[11];
    const float* rp_w  = (const float*)d_in[12];
    const float* rp_b  = (const float*)d_in[13];
    const float* rp_lnw= (const float*)d_in[14];
    const float* rp_lnb= (const float*)d_in[15];
    const float* pp_w  = (const float*)d_in[16];
    const float* pp_b  = (const float*)d_in[17];
    const float* pp_lnw= (const float*)d_in[18];
    const float* pp_lnb= (const float*)d_in[19];
    const float* pr_w0 = (const float*)d_in[20];
    const float* pr_b0 = (const float*)d_in[21];
    const float* pr_w1 = (const float*)d_in[22];
    const float* pr_b1 = (const float*)d_in[23];
    // d_in[24] = pstep (always 2)

    float* ws      = (float*)d_ws;
    float* nr      = ws;                       // 262144 each
    float* ns      = nr + ROWS * 128;
    float* recvT   = ns + ROWS * 128;
    float* sendT   = recvT + ROWS * 128;
    float* recvT1  = sendT + ROWS * 128;
    float* sendT1  = recvT1 + ROWS * 128;
    float* recvS0  = sendT1 + ROWS * 128;      // 2048 each
    float* sendS0  = recvS0 + ROWS;
    float* recvS1v = sendS0 + ROWS;
    float* sendS1v = recvS1v + ROWS;
    float* rowsumE = sendS1v + ROWS;           // 131072
    u16* wsumb  = (u16*)(rowsumE + ROWS * 64);
    u16* re_w1b = wsumb + 128;
    u16* web    = re_w1b + 16384;
    u16* pp_wT  = web + 16384;                 // 32768
    u16* wrecvT = pp_wT + 32768;
    u16* wsendT = wrecvT + 16384;
    u16* pr_w0T = wsendT + 16384;
    u16* pr_w1T = pr_w0T + 16384;              // 4096
    u16* objb   = pr_w1T + 4096;               // 262144
    u16* obj1b  = objb + ROWS * 128;           // 262144
    u16* Ebuf   = obj1b + ROWS * 128;          // 33.5 MB

    k_node<<<128, 256, 0, stream>>>(attrs, states, oe_w0, oe_b0, oe_w1, oe_b1,
                                    re_w0, re_b0, rp_w, rp_b,
                                    re_w1, pp_w, pr_w0, pr_w1,
                                    re_w1b, web, pp_wT, wrecvT, wsendT, pr_w0T, pr_w1T, wsumb,
                                    objb, nr, ns, recvT, sendT, recvS0, sendS0);
    k_edge_fused<<<2048, 256, 0, stream>>>(rel_attrs, re_w0, re_w1b, web, wsumb, re_b1,
                                           rp_lnw, rp_lnb, nr, ns, recvT, sendT,
                                           recvS0, sendS0, objb,
                                           pp_wT, pp_b, pp_lnw, pp_lnb,
                                           wrecvT, wsendT, rp_b,
                                           Ebuf, rowsumE, obj1b, recvT1, sendT1,
                                           recvS1v, sendS1v);
    k_prop_edge2<<<2048, 256, 0, stream>>>(Ebuf, rowsumE, rp_lnw, rp_lnb,
                                           recvT1, sendT1, recvS1v, sendS1v,
                                           obj1b, pp_wT, pp_b, pp_lnw, pp_lnb,
                                           pr_w0T, pr_b0, pr_w1T, pr_b1, (float*)d_out);
}

// Round 12
// 186.325 us; speedup vs baseline: 1.1189x; 1.1189x over previous
//
#include <hip/hip_runtime.h>
#include <hip/hip_bf16.h>

// CompositionalKoopmanOperators: B=32,N=64,ATTR=4,STATE=8,REL=4,GDIM=32,NF=128,pstep=2
// Round 12: r9 structure (5 kernels, best family) + one change: edge_fused
// prefetches the y-phase operands (recvT row, 32 sendT scalars, recvS0) into
// registers at kernel top so their ~200-400cyc latency hides under phase-1 and
// both GEMMs instead of being exposed after GEMM2.

#define ROWS 2048   // B*N
typedef unsigned short u16;
typedef unsigned int u32;
typedef __attribute__((ext_vector_type(8))) short bf16x8;   // 8 bf16 = 4 VGPR
typedef __attribute__((ext_vector_type(4))) float f32x4;

__device__ __forceinline__ float bsu(u16 u) { return __uint_as_float(((u32)u) << 16); }
__device__ __forceinline__ u16 f2b(float f) {
    u32 u = __float_as_uint(f);
    u32 r = (u + 0x7fffu + ((u >> 16) & 1u)) >> 16;   // RNE
    return (u16)r;
}
__device__ __forceinline__ u32 pk2(float a, float b) {   // packed RNE cvt
    __hip_bfloat162 h = __float22bfloat162_rn(float2{a, b});
    union { __hip_bfloat162 h; u32 u; } c; c.h = h; return c.u;
}
__device__ __forceinline__ bf16x8 ldcvt8(const float* __restrict__ p) {  // 8 f32 -> bf16x8
    float4 a = *(const float4*)p;
    float4 b = *(const float4*)(p + 4);
    union { u32 u[4]; bf16x8 v; } x;
    x.u[0] = pk2(a.x, a.y); x.u[1] = pk2(a.z, a.w);
    x.u[2] = pk2(b.x, b.y); x.u[3] = pk2(b.z, b.w);
    return x.v;
}

// ---------------- k_node: prep (weight cvt) + L0 + 3 MFMA GEMMs ----------------
__global__ __launch_bounds__(256)
void k_node(const float* __restrict__ attrs, const float* __restrict__ states,
            const float* __restrict__ oe_w0, const float* __restrict__ oe_b0,
            const float* __restrict__ oe_w1, const float* __restrict__ oe_b1,
            const float* __restrict__ re_w0, const float* __restrict__ re_b0,
            const float* __restrict__ rp_w,  const float* __restrict__ rp_b,
            const float* __restrict__ re_w1, const float* __restrict__ pp_w,
            const float* __restrict__ pr_w0, const float* __restrict__ pr_w1,
            u16* __restrict__ re_w1b, u16* __restrict__ web, u16* __restrict__ pp_wb,
            u16* __restrict__ wrecvb, u16* __restrict__ wsendb,
            u16* __restrict__ pr_w0b, u16* __restrict__ pr_w1b,
            u16* __restrict__ objb, float* __restrict__ nr, float* __restrict__ ns,
            float* __restrict__ recvT, float* __restrict__ sendT)
{
    const int r0 = blockIdx.x * 16;
    const int t = threadIdx.x;
    __shared__ float xs[16][12];
    __shared__ float w0s[1536];
    __shared__ float rw0s[2560];
    __shared__ __align__(16) u16 hb[16 * 136];
    __shared__ __align__(16) u16 ob[16 * 136];

    // ---- distributed weight prep (118784 values over 32768 threads) ----
    {
        int gid = blockIdx.x * 256 + t;
        for (int i = gid; i < 118784; i += 32768) {
            int idx = i;
            if (idx < 16384) { re_w1b[idx] = f2b(re_w1[idx]); continue; }
            idx -= 16384;
            if (idx < 16384) { web[idx] = f2b(rp_w[(idx >> 7) * 384 + (idx & 127)]); continue; }
            idx -= 16384;
            if (idx < 32768) { pp_wb[idx] = f2b(pp_w[idx]); continue; }
            idx -= 32768;
            if (idx < 16384) { wrecvb[idx] = f2b(rp_w[(idx >> 7) * 384 + 128 + (idx & 127)]); continue; }
            idx -= 16384;
            if (idx < 16384) { wsendb[idx] = f2b(rp_w[(idx >> 7) * 384 + 256 + (idx & 127)]); continue; }
            idx -= 16384;
            if (idx < 16384) { pr_w0b[idx] = f2b(pr_w0[idx]); continue; }
            idx -= 16384;
            pr_w1b[idx] = f2b(pr_w1[idx]);
        }
    }

    if (t < 192) { int row = t / 12, c = t - row * 12;
        xs[row][c] = (c < 4) ? attrs[(r0 + row) * 4 + c] : states[(r0 + row) * 8 + (c - 4)]; }
    for (int i = t; i < 1536; i += 256) w0s[i] = oe_w0[i];
    for (int i = t; i < 2560; i += 256) rw0s[i] = re_w0[i];
    __syncthreads();

    for (int e = t; e < 2048; e += 256) {
        int row = e >> 7, o = e & 127;
        float h = oe_b0[o];
#pragma unroll
        for (int k = 0; k < 12; k++) h += w0s[o * 12 + k] * xs[row][k];
        hb[row * 136 + o] = f2b(fmaxf(h, 0.f));
        float s0 = 0.f, a0 = 0.f, a1 = 0.f;
#pragma unroll
        for (int k = 0; k < 8; k++) s0 += rw0s[o * 20 + 4 + k] * xs[row][4 + k];
#pragma unroll
        for (int k = 0; k < 4; k++) {
            a0 += rw0s[o * 20 + 12 + k] * xs[row][k];
            a1 += rw0s[o * 20 + 16 + k] * xs[row][k];
        }
        nr[(r0 + row) * 128 + o] = s0 + a0 + re_b0[o];
        ns[(r0 + row) * 128 + o] = a1 - s0;
    }
    __syncthreads();

    const int wave = t >> 6, lane = t & 63, tx = lane & 15, quad = lane >> 4;

    bf16x8 afr[4];
#pragma unroll
    for (int kk = 0; kk < 4; kk++) afr[kk] = *(const bf16x8*)&hb[tx * 136 + kk * 32 + quad * 8];
    f32x4 acc[2]; acc[0] = (f32x4){0.f,0.f,0.f,0.f}; acc[1] = acc[0];
#pragma unroll
    for (int ot = 0; ot < 2; ot++) {
        int o = (wave * 2 + ot) * 16 + tx;
#pragma unroll
        for (int kk = 0; kk < 4; kk++) {
            bf16x8 bfr = ldcvt8(&oe_w1[o * 128 + kk * 32 + quad * 8]);
            acc[ot] = __builtin_amdgcn_mfma_f32_16x16x32_bf16(afr[kk], bfr, acc[ot], 0, 0, 0);
        }
    }
#pragma unroll
    for (int ot = 0; ot < 2; ot++) {
        int o = (wave * 2 + ot) * 16 + tx;
        float bia = oe_b1[o];
#pragma unroll
        for (int r = 0; r < 4; r++)
            ob[(quad * 4 + r) * 136 + o] = f2b(fmaxf(acc[ot][r] + bia, 0.f));
    }
    __syncthreads();
    { int m = t >> 4, c = t & 15;
      *(uint4*)&objb[(r0 + m) * 128 + c * 8] = *(const uint4*)&ob[m * 136 + c * 8]; }

#pragma unroll
    for (int kk = 0; kk < 4; kk++) afr[kk] = *(const bf16x8*)&ob[tx * 136 + kk * 32 + quad * 8];
    f32x4 ar[2], an[2];
    ar[0] = (f32x4){0.f,0.f,0.f,0.f}; ar[1] = ar[0]; an[0] = ar[0]; an[1] = ar[0];
#pragma unroll
    for (int ot = 0; ot < 2; ot++) {
        int o = (wave * 2 + ot) * 16 + tx;
#pragma unroll
        for (int kk = 0; kk < 4; kk++) {
            bf16x8 br = ldcvt8(&rp_w[o * 384 + 128 + kk * 32 + quad * 8]);
            ar[ot] = __builtin_amdgcn_mfma_f32_16x16x32_bf16(afr[kk], br, ar[ot], 0, 0, 0);
            bf16x8 bs = ldcvt8(&rp_w[o * 384 + 256 + kk * 32 + quad * 8]);
            an[ot] = __builtin_amdgcn_mfma_f32_16x16x32_bf16(afr[kk], bs, an[ot], 0, 0, 0);
        }
    }
#pragma unroll
    for (int ot = 0; ot < 2; ot++) {
        int o = (wave * 2 + ot) * 16 + tx;
        float rb = rp_b[o];
#pragma unroll
        for (int r = 0; r < 4; r++) {
            recvT[(r0 + quad * 4 + r) * 128 + o] = ar[ot][r] + rb;
            sendT[(r0 + quad * 4 + r) * 128 + o] = an[ot][r];
        }
    }
}

// ---------------- k_edge_fused (r12): fast phase-1, B in registers, y-operand prefetch ----
__global__ __launch_bounds__(256)
void k_edge_fused(const float* __restrict__ rel_attrs,
                  const float* __restrict__ re_w0, const u16* __restrict__ re_w1b,
                  const u16* __restrict__ web, const float* __restrict__ re_b1,
                  const float* __restrict__ rp_lnw, const float* __restrict__ rp_lnb,
                  const float* __restrict__ nr, const float* __restrict__ ns,
                  const float* __restrict__ recvT, const float* __restrict__ sendT,
                  u16* __restrict__ Ebuf, u16* __restrict__ aggb)
{
    const int blkg = blockIdx.x;    // b*64 + i
    const int b = blkg >> 6;
    const int t = threadIdx.x;
    __shared__ __align__(16) u16 hsb[64 * 144];     // h0, then relE (18432 B)
    __shared__ float lnws[128], lnbs[128];
    __shared__ float redS[256], redQ[256];          // [wave][row]

    if (t < 128) { lnws[t] = rp_lnw[t]; lnbs[t] = rp_lnb[t]; }

    const int w = t >> 6, lane = t & 63, tx = lane & 15, quad = lane >> 4;
    const int ob = w * 32;              // this wave's output-column base

    // ---- EARLY ISSUE: y-phase operands (consumed after GEMM2; latency hidden) ----
    float rv0 = recvT[blkg * 128 + ob + tx];
    float rv1 = recvT[blkg * 128 + ob + 16 + tx];
    float ps0[4][4], ps1[4][4];
#pragma unroll
    for (int jt = 0; jt < 4; jt++)
#pragma unroll
        for (int r = 0; r < 4; r++) {
            int j = b * 64 + jt * 16 + quad * 4 + r;
            ps0[jt][r] = sendT[j * 128 + ob + tx];
            ps1[jt][r] = sendT[j * 128 + ob + 16 + tx];
        }

    // ---- phase 1: h0[j][o], 8-col slice per thread, register-held weights ----
    {
        const int o0 = (t & 15) * 8;
        const int jb = t >> 4;
        float4 nr0 = *(const float4*)&nr[blkg * 128 + o0];
        float4 nr1 = *(const float4*)&nr[blkg * 128 + o0 + 4];
        float4 wreg[8];
#pragma unroll
        for (int k = 0; k < 8; k++) wreg[k] = *(const float4*)&re_w0[(o0 + k) * 20];
#pragma unroll
        for (int it = 0; it < 4; it++) {
            int j = jb + it * 16;
            float4 ra = *(const float4*)&rel_attrs[((size_t)blkg * 64 + j) * 4];
            const float* nsp = &ns[(b * 64 + j) * 128 + o0];
            float4 na = *(const float4*)nsp;
            float4 nb = *(const float4*)(nsp + 4);
            float v[8];
            v[0] = nr0.x + na.x; v[1] = nr0.y + na.y; v[2] = nr0.z + na.z; v[3] = nr0.w + na.w;
            v[4] = nr1.x + nb.x; v[5] = nr1.y + nb.y; v[6] = nr1.z + nb.z; v[7] = nr1.w + nb.w;
#pragma unroll
            for (int k = 0; k < 8; k++) {
                v[k] += wreg[k].x * ra.x + wreg[k].y * ra.y + wreg[k].z * ra.z + wreg[k].w * ra.w;
                v[k] = fmaxf(v[k], 0.f);
            }
            union { u32 u[4]; uint4 q; } p;
            p.u[0] = pk2(v[0], v[1]); p.u[1] = pk2(v[2], v[3]);
            p.u[2] = pk2(v[4], v[5]); p.u[3] = pk2(v[6], v[7]);
            *(uint4*)&hsb[j * 144 + o0] = p.q;
        }
    }

    // B1 fragments (bf16, prepped): registers for whole GEMM
    bf16x8 b1[2][4];
#pragma unroll
    for (int ot = 0; ot < 2; ot++)
#pragma unroll
        for (int kk = 0; kk < 4; kk++)
            b1[ot][kk] = *(const bf16x8*)&re_w1b[(ob + ot * 16 + tx) * 128 + kk * 32 + quad * 8];
    __syncthreads();

    // GEMM1
    f32x4 acc[4][2];
#pragma unroll
    for (int jt = 0; jt < 4; jt++) { acc[jt][0] = (f32x4){0.f,0.f,0.f,0.f}; acc[jt][1] = acc[jt][0]; }
#pragma unroll
    for (int jt = 0; jt < 4; jt++) {
        bf16x8 afr[4];
#pragma unroll
        for (int kk = 0; kk < 4; kk++)
            afr[kk] = *(const bf16x8*)&hsb[(jt * 16 + tx) * 144 + kk * 32 + quad * 8];
#pragma unroll
        for (int ot = 0; ot < 2; ot++)
#pragma unroll
            for (int kk = 0; kk < 4; kk++)
                acc[jt][ot] = __builtin_amdgcn_mfma_f32_16x16x32_bf16(afr[kk], b1[ot][kk], acc[jt][ot], 0, 0, 0);
    }
    __syncthreads();

    // epilogue1: relu(acc + bias) -> relE back into hsb
    {
        float bia0 = re_b1[ob + tx], bia1 = re_b1[ob + 16 + tx];
#pragma unroll
        for (int jt = 0; jt < 4; jt++)
#pragma unroll
            for (int r = 0; r < 4; r++) {
                int j = jt * 16 + quad * 4 + r;
                hsb[j * 144 + ob + tx]      = f2b(fmaxf(acc[jt][0][r] + bia0, 0.f));
                hsb[j * 144 + ob + 16 + tx] = f2b(fmaxf(acc[jt][1][r] + bia1, 0.f));
            }
    }
    bf16x8 b2[2][4];
#pragma unroll
    for (int ot = 0; ot < 2; ot++)
#pragma unroll
        for (int kk = 0; kk < 4; kk++)
            b2[ot][kk] = *(const bf16x8*)&web[(ob + ot * 16 + tx) * 128 + kk * 32 + quad * 8];
    __syncthreads();

    // GEMM2
    f32x4 acc2[4][2];
#pragma unroll
    for (int jt = 0; jt < 4; jt++) { acc2[jt][0] = (f32x4){0.f,0.f,0.f,0.f}; acc2[jt][1] = acc2[jt][0]; }
#pragma unroll
    for (int jt = 0; jt < 4; jt++) {
        bf16x8 afr[4];
#pragma unroll
        for (int kk = 0; kk < 4; kk++)
            afr[kk] = *(const bf16x8*)&hsb[(jt * 16 + tx) * 144 + kk * 32 + quad * 8];
#pragma unroll
        for (int ot = 0; ot < 2; ot++)
#pragma unroll
            for (int kk = 0; kk < 4; kk++)
                acc2[jt][ot] = __builtin_amdgcn_mfma_f32_16x16x32_bf16(afr[kk], b2[ot][kk], acc2[jt][ot], 0, 0, 0);
    }

    // store E (pre recv/send), packed cvt, prop_edge2-compatible fragment order
#pragma unroll
    for (int jt = 0; jt < 4; jt++)
#pragma unroll
        for (int ot = 0; ot < 2; ot++) {
            uint2 ev;
            ev.x = pk2(acc2[jt][ot][0], acc2[jt][ot][1]);
            ev.y = pk2(acc2[jt][ot][2], acc2[jt][ot][3]);
            *(uint2*)(Ebuf + ((size_t)((blkg * 4 + jt) * 8 + (2 * w + ot)) * 64 + lane) * 4) = ev;
        }

    // y = E + recvT[i][o] + sendT[j][o]   (operands prefetched)
#pragma unroll
    for (int jt = 0; jt < 4; jt++)
#pragma unroll
        for (int r = 0; r < 4; r++) {
            acc2[jt][0][r] += rv0 + ps0[jt][r];
            acc2[jt][1][r] += rv1 + ps1[jt][r];
        }

    // LN row partials -> LDS
#pragma unroll
    for (int jt = 0; jt < 4; jt++) {
        float s4[4], q4[4];
#pragma unroll
        for (int r = 0; r < 4; r++) {
            float a0 = acc2[jt][0][r], a1 = acc2[jt][1][r];
            s4[r] = a0 + a1; q4[r] = a0 * a0 + a1 * a1;
        }
#pragma unroll
        for (int m = 1; m < 16; m <<= 1)
#pragma unroll
            for (int r = 0; r < 4; r++) {
                s4[r] += __shfl_xor(s4[r], m, 64);
                q4[r] += __shfl_xor(q4[r], m, 64);
            }
        if (tx == 0)
#pragma unroll
            for (int r = 0; r < 4; r++) {
                redS[w * 64 + jt * 16 + quad * 4 + r] = s4[r];
                redQ[w * 64 + jt * 16 + quad * 4 + r] = q4[r];
            }
    }
    __syncthreads();

    // normalize + relu + per-col agg
    {
        float lw0 = lnws[ob + tx], lb0 = lnbs[ob + tx];
        float lw1 = lnws[ob + 16 + tx], lb1 = lnbs[ob + 16 + tx];
        float ag0 = 0.f, ag1 = 0.f;
#pragma unroll
        for (int jt = 0; jt < 4; jt++)
#pragma unroll
            for (int r = 0; r < 4; r++) {
                int row = jt * 16 + quad * 4 + r;
                float ss = redS[row] + redS[64 + row] + redS[128 + row] + redS[192 + row];
                float qq = redQ[row] + redQ[64 + row] + redQ[128 + row] + redQ[192 + row];
                float mu = ss * (1.f / 128.f);
                float rsd = rsqrtf(qq * (1.f / 128.f) - mu * mu + 1e-5f);
                float z0 = (acc2[jt][0][r] - mu) * rsd * lw0 + lb0;
                float z1 = (acc2[jt][1][r] - mu) * rsd * lw1 + lb1;
                ag0 += fmaxf(z0, 0.f);
                ag1 += fmaxf(z1, 0.f);
            }
        ag0 += __shfl_xor(ag0, 16, 64); ag0 += __shfl_xor(ag0, 32, 64);
        ag1 += __shfl_xor(ag1, 16, 64); ag1 += __shfl_xor(ag1, 32, 64);
        if (quad == 0) {
            aggb[blkg * 128 + ob + tx]      = f2b(ag0);
            aggb[blkg * 128 + ob + 16 + tx] = f2b(ag1);
        }
    }
}

// ---------------- k_prop_edge2: step-1, no GEMM ----------------
__global__ __launch_bounds__(256)
void k_prop_edge2(const u16* __restrict__ Ebuf,
                  const float* __restrict__ rp_lnw, const float* __restrict__ rp_lnb,
                  const float* __restrict__ recvT, const float* __restrict__ sendT,
                  u16* __restrict__ aggb)
{
    const int blk = blockIdx.x;   // b*64 + i
    const int b = blk >> 6;
    const int t = threadIdx.x;
    __shared__ float scr[16 * 132];
    __shared__ float lnws[128], lnbs[128];
    if (t < 128) { lnws[t] = rp_lnw[t]; lnbs[t] = rp_lnb[t]; }
    __syncthreads();

    const int wave = t >> 6, lane = t & 63, tx = lane & 15, quad = lane >> 4;
    const int tid = blk * 4 + wave;
    const int jrow = wave * 16 + quad * 4;

    float y[8][4];
#pragma unroll
    for (int oo = 0; oo < 8; oo++) {
        uint2 ev = *(const uint2*)(Ebuf + ((size_t)(tid * 8 + oo) * 64 + lane) * 4);
        const int o = oo * 16 + tx;
        float rv = recvT[blk * 128 + o];
        float e0 = bsu((u16)(ev.x & 0xffff)), e1 = bsu((u16)(ev.x >> 16));
        float e2 = bsu((u16)(ev.y & 0xffff)), e3 = bsu((u16)(ev.y >> 16));
        y[oo][0] = e0 + rv + sendT[(b * 64 + jrow + 0) * 128 + o];
        y[oo][1] = e1 + rv + sendT[(b * 64 + jrow + 1) * 128 + o];
        y[oo][2] = e2 + rv + sendT[(b * 64 + jrow + 2) * 128 + o];
        y[oo][3] = e3 + rv + sendT[(b * 64 + jrow + 3) * 128 + o];
    }
    float s[4], q[4];
#pragma unroll
    for (int r = 0; r < 4; r++) {
        s[r] = 0.f; q[r] = 0.f;
#pragma unroll
        for (int oo = 0; oo < 8; oo++) { s[r] += y[oo][r]; q[r] += y[oo][r] * y[oo][r]; }
    }
#pragma unroll
    for (int m = 1; m < 16; m <<= 1) {
#pragma unroll
        for (int r = 0; r < 4; r++) {
            s[r] += __shfl_xor(s[r], m, 64);
            q[r] += __shfl_xor(q[r], m, 64);
        }
    }
    float mu[4], rs[4];
#pragma unroll
    for (int r = 0; r < 4; r++) {
        mu[r] = s[r] * (1.f / 128.f);
        rs[r] = rsqrtf(q[r] * (1.f / 128.f) - mu[r] * mu[r] + 1e-5f);
    }
    float pa[8];
#pragma unroll
    for (int oo = 0; oo < 8; oo++) {
        const int o = oo * 16 + tx;
        float lw = lnws[o], lb = lnbs[o];
        float p = 0.f;
#pragma unroll
        for (int r = 0; r < 4; r++) {
            float z = (y[oo][r] - mu[r]) * rs[r] * lw + lb;
            p += fmaxf(z, 0.f);
        }
        pa[oo] = p;
    }
    const int grp = wave * 4 + quad;
#pragma unroll
    for (int oo = 0; oo < 8; oo++) scr[grp * 132 + oo * 16 + tx] = pa[oo];
    __syncthreads();
    if (t < 128) {
        float sum = 0.f;
#pragma unroll
        for (int gg = 0; gg < 16; gg++) sum += scr[gg * 132 + t];
        aggb[blk * 128 + t] = f2b(sum);
    }
}

// ---------------- k_pn0: prop step 0 node (pp + LN + relu + next recv/send terms) ----
__global__ __launch_bounds__(256)
void k_pn0(const u16* __restrict__ aggb,
           const u16* __restrict__ pp_wb, const float* __restrict__ pp_b,
           const float* __restrict__ pp_lnw, const float* __restrict__ pp_lnb,
           const u16* __restrict__ wrecvb, const u16* __restrict__ wsendb,
           const float* __restrict__ rp_b,
           u16* __restrict__ objb, float* __restrict__ recvT, float* __restrict__ sendT)
{
    const int r0 = blockIdx.x * 16;
    const int t = threadIdx.x;
    __shared__ __align__(16) u16 ab[16 * 264];
    __shared__ __align__(16) u16 ob[16 * 136];
    __shared__ float redS[64], redQ[64];

    for (int i = t; i < 512; i += 256) {
        int m = i >> 5, c = i & 31;
        uint4 v = (c < 16) ? *(const uint4*)&objb[(r0 + m) * 128 + (c & 15) * 8]
                           : *(const uint4*)&aggb[(r0 + m) * 128 + (c - 16) * 8];
        *(uint4*)&ab[m * 264 + c * 8] = v;
    }
    __syncthreads();

    const int wave = t >> 6, lane = t & 63, tx = lane & 15, quad = lane >> 4;
    bf16x8 afr[8];
#pragma unroll
    for (int kk = 0; kk < 8; kk++) afr[kk] = *(const bf16x8*)&ab[tx * 264 + kk * 32 + quad * 8];
    f32x4 acc[2]; acc[0] = (f32x4){0.f,0.f,0.f,0.f}; acc[1] = acc[0];
#pragma unroll
    for (int ot = 0; ot < 2; ot++) {
        int o = (wave * 2 + ot) * 16 + tx;
#pragma unroll
        for (int kk = 0; kk < 8; kk++) {
            bf16x8 bfr = *(const bf16x8*)&pp_wb[o * 256 + kk * 32 + quad * 8];
            acc[ot] = __builtin_amdgcn_mfma_f32_16x16x32_bf16(afr[kk], bfr, acc[ot], 0, 0, 0);
        }
    }
#pragma unroll
    for (int ot = 0; ot < 2; ot++) {
        float bia = pp_b[(wave * 2 + ot) * 16 + tx];
#pragma unroll
        for (int r = 0; r < 4; r++) acc[ot][r] += bia;
    }

    float s[4], q[4];
#pragma unroll
    for (int r = 0; r < 4; r++) {
        s[r] = acc[0][r] + acc[1][r];
        q[r] = acc[0][r] * acc[0][r] + acc[1][r] * acc[1][r];
    }
#pragma unroll
    for (int m = 1; m < 16; m <<= 1) {
#pragma unroll
        for (int r = 0; r < 4; r++) {
            s[r] += __shfl_xor(s[r], m, 64);
            q[r] += __shfl_xor(q[r], m, 64);
        }
    }
    if (tx == 0) {
#pragma unroll
        for (int r = 0; r < 4; r++) {
            redS[wave * 16 + quad * 4 + r] = s[r];
            redQ[wave * 16 + quad * 4 + r] = q[r];
        }
    }
    __syncthreads();
    float mu[4], rs[4];
#pragma unroll
    for (int r = 0; r < 4; r++) {
        int m = quad * 4 + r;
        float ss = redS[m] + redS[16 + m] + redS[32 + m] + redS[48 + m];
        float qq = redQ[m] + redQ[16 + m] + redQ[32 + m] + redQ[48 + m];
        mu[r] = ss * (1.f / 128.f);
        rs[r] = rsqrtf(qq * (1.f / 128.f) - mu[r] * mu[r] + 1e-5f);
    }
#pragma unroll
    for (int ot = 0; ot < 2; ot++) {
        int o = (wave * 2 + ot) * 16 + tx;
        float lw = pp_lnw[o], lb = pp_lnb[o];
#pragma unroll
        for (int r = 0; r < 4; r++) {
            float z = (acc[ot][r] - mu[r]) * rs[r] * lw + lb;
            ob[(quad * 4 + r) * 136 + o] = f2b(fmaxf(z, 0.f));
        }
    }
    __syncthreads();
    { int m = t >> 4, c = t & 15;
      *(uint4*)&objb[(r0 + m) * 128 + c * 8] = *(const uint4*)&ob[m * 136 + c * 8]; }

    bf16x8 af2[4];
#pragma unroll
    for (int kk = 0; kk < 4; kk++) af2[kk] = *(const bf16x8*)&ob[tx * 136 + kk * 32 + quad * 8];
    f32x4 ar[2], an[2];
    ar[0] = (f32x4){0.f,0.f,0.f,0.f}; ar[1] = ar[0]; an[0] = ar[0]; an[1] = ar[0];
#pragma unroll
    for (int ot = 0; ot < 2; ot++) {
        int o = (wave * 2 + ot) * 16 + tx;
#pragma unroll
        for (int kk = 0; kk < 4; kk++) {
            bf16x8 br = *(const bf16x8*)&wrecvb[o * 128 + kk * 32 + quad * 8];
            ar[ot] = __builtin_amdgcn_mfma_f32_16x16x32_bf16(af2[kk], br, ar[ot], 0, 0, 0);
            bf16x8 bs = *(const bf16x8*)&wsendb[o * 128 + kk * 32 + quad * 8];
            an[ot] = __builtin_amdgcn_mfma_f32_16x16x32_bf16(af2[kk], bs, an[ot], 0, 0, 0);
        }
    }
#pragma unroll
    for (int ot = 0; ot < 2; ot++) {
        int o = (wave * 2 + ot) * 16 + tx;
        float rb = rp_b[o];
#pragma unroll
        for (int r = 0; r < 4; r++) {
            recvT[(r0 + quad * 4 + r) * 128 + o] = ar[ot][r] + rb;
            sendT[(r0 + quad * 4 + r) * 128 + o] = an[ot][r];
        }
    }
}

// ---------------- k_pn1pred: prop step 1 node + predictor + tanh, fused ----------------
__global__ __launch_bounds__(256)
void k_pn1pred(const u16* __restrict__ aggb,
               const u16* __restrict__ pp_wb, const float* __restrict__ pp_b,
               const float* __restrict__ pp_lnw, const float* __restrict__ pp_lnb,
               const u16* __restrict__ objb,
               const u16* __restrict__ pr_w0b, const float* __restrict__ pr_b0,
               const u16* __restrict__ pr_w1b, const float* __restrict__ pr_b1,
               float* __restrict__ out)
{
    const int r0 = blockIdx.x * 16;
    const int t = threadIdx.x;
    __shared__ __align__(16) u16 ab[16 * 264];
    __shared__ __align__(16) u16 ob[16 * 136];
    __shared__ __align__(16) u16 hb2[16 * 136];
    __shared__ float redS[64], redQ[64];

    for (int i = t; i < 512; i += 256) {
        int m = i >> 5, c = i & 31;
        uint4 v = (c < 16) ? *(const uint4*)&objb[(r0 + m) * 128 + (c & 15) * 8]
                           : *(const uint4*)&aggb[(r0 + m) * 128 + (c - 16) * 8];
        *(uint4*)&ab[m * 264 + c * 8] = v;
    }
    __syncthreads();

    const int wave = t >> 6, lane = t & 63, tx = lane & 15, quad = lane >> 4;
    bf16x8 afr[8];
#pragma unroll
    for (int kk = 0; kk < 8; kk++) afr[kk] = *(const bf16x8*)&ab[tx * 264 + kk * 32 + quad * 8];
    f32x4 acc[2]; acc[0] = (f32x4){0.f,0.f,0.f,0.f}; acc[1] = acc[0];
#pragma unroll
    for (int ot = 0; ot < 2; ot++) {
        int o = (wave * 2 + ot) * 16 + tx;
#pragma unroll
        for (int kk = 0; kk < 8; kk++) {
            bf16x8 bfr = *(const bf16x8*)&pp_wb[o * 256 + kk * 32 + quad * 8];
            acc[ot] = __builtin_amdgcn_mfma_f32_16x16x32_bf16(afr[kk], bfr, acc[ot], 0, 0, 0);
        }
    }
#pragma unroll
    for (int ot = 0; ot < 2; ot++) {
        float bia = pp_b[(wave * 2 + ot) * 16 + tx];
#pragma unroll
        for (int r = 0; r < 4; r++) acc[ot][r] += bia;
    }

    float s[4], q[4];
#pragma unroll
    for (int r = 0; r < 4; r++) {
        s[r] = acc[0][r] + acc[1][r];
        q[r] = acc[0][r] * acc[0][r] + acc[1][r] * acc[1][r];
    }
#pragma unroll
    for (int m = 1; m < 16; m <<= 1) {
#pragma unroll
        for (int r = 0; r < 4; r++) {
            s[r] += __shfl_xor(s[r], m, 64);
            q[r] += __shfl_xor(q[r], m, 64);
        }
    }
    if (tx == 0) {
#pragma unroll
        for (int r = 0; r < 4; r++) {
            redS[wave * 16 + quad * 4 + r] = s[r];
            redQ[wave * 16 + quad * 4 + r] = q[r];
        }
    }
    __syncthreads();
    float mu[4], rs[4];
#pragma unroll
    for (int r = 0; r < 4; r++) {
        int m = quad * 4 + r;
        float ss = redS[m] + redS[16 + m] + redS[32 + m] + redS[48 + m];
        float qq = redQ[m] + redQ[16 + m] + redQ[32 + m] + redQ[48 + m];
        mu[r] = ss * (1.f / 128.f);
        rs[r] = rsqrtf(qq * (1.f / 128.f) - mu[r] * mu[r] + 1e-5f);
    }
#pragma unroll
    for (int ot = 0; ot < 2; ot++) {
        int o = (wave * 2 + ot) * 16 + tx;
        float lw = pp_lnw[o], lb = pp_lnb[o];
#pragma unroll
        for (int r = 0; r < 4; r++) {
            float z = (acc[ot][r] - mu[r]) * rs[r] * lw + lb;
            ob[(quad * 4 + r) * 136 + o] = f2b(fmaxf(z, 0.f));
        }
    }
    __syncthreads();

    // ---- predictor layer 0: h = relu(obj @ pr_w0^T + b0) ----
    bf16x8 af2[4];
#pragma unroll
    for (int kk = 0; kk < 4; kk++) af2[kk] = *(const bf16x8*)&ob[tx * 136 + kk * 32 + quad * 8];
    f32x4 ah[2]; ah[0] = (f32x4){0.f,0.f,0.f,0.f}; ah[1] = ah[0];
#pragma unroll
    for (int ot = 0; ot < 2; ot++) {
        int o = (wave * 2 + ot) * 16 + tx;
#pragma unroll
        for (int kk = 0; kk < 4; kk++) {
            bf16x8 bfr = *(const bf16x8*)&pr_w0b[o * 128 + kk * 32 + quad * 8];
            ah[ot] = __builtin_amdgcn_mfma_f32_16x16x32_bf16(af2[kk], bfr, ah[ot], 0, 0, 0);
        }
    }
#pragma unroll
    for (int ot = 0; ot < 2; ot++) {
        int o = (wave * 2 + ot) * 16 + tx;
        float bia = pr_b0[o];
#pragma unroll
        for (int r = 0; r < 4; r++)
            hb2[(quad * 4 + r) * 136 + o] = f2b(fmaxf(ah[ot][r] + bia, 0.f));
    }
    __syncthreads();

    // ---- predictor layer 1 (GDIM=32) + tanh ----
    if (wave < 2) {
        bf16x8 af3[4];
#pragma unroll
        for (int kk = 0; kk < 4; kk++) af3[kk] = *(const bf16x8*)&hb2[tx * 136 + kk * 32 + quad * 8];
        f32x4 a2 = (f32x4){0.f,0.f,0.f,0.f};
        int o = wave * 16 + tx;
#pragma unroll
        for (int kk = 0; kk < 4; kk++) {
            bf16x8 bfr = *(const bf16x8*)&pr_w1b[o * 128 + kk * 32 + quad * 8];
            a2 = __builtin_amdgcn_mfma_f32_16x16x32_bf16(af3[kk], bfr, a2, 0, 0, 0);
        }
        float bia = pr_b1[o];
#pragma unroll
        for (int r = 0; r < 4; r++)
            out[(r0 + quad * 4 + r) * 32 + o] = tanhf(a2[r] + bia);
    }
}

extern "C" void kernel_launch(void* const* d_in, const int* in_sizes, int n_in,
                              void* d_out, int out_size, void* d_ws, size_t ws_size,
                              hipStream_t stream)
{
    const float* attrs    = (const float*)d_in[0];
    const float* states   = (const float*)d_in[1];
    const float* rel_attrs= (const float*)d_in[3];
    const float* oe_w0 = (const float*)d_in[4];
    const float* oe_b0 = (const float*)d_in[5];
    const float* oe_w1 = (const float*)d_in[6];
    const float* oe_b1 = (const float*)d_in[7];
    const float* re_w0 = (const float*)d_in[8];
    const float* re_b0 = (const float*)d_in[9];
    const float* re_w1 = (const float*)d_in[10];
    const float* re_b1 = (const float*)d_in[11];
    const float* rp_w  = (const float*)d_in[12];
    const float* rp_b  = (const float*)d_in[13];
    const float* rp_lnw= (const float*)d_in[14];
    const float* rp_lnb= (const float*)d_in[15];
    const float* pp_w  = (const float*)d_in[16];
    const float* pp_b  = (const float*)d_in[17];
    const float* pp_lnw= (const float*)d_in[18];
    const float* pp_lnb= (const float*)d_in[19];
    const float* pr_w0 = (const float*)d_in[20];
    const float* pr_b0 = (const float*)d_in[21];
    const float* pr_w1 = (const float*)d_in[22];
    const float* pr_b1 = (const float*)d_in[23];
    // d_in[24] = pstep (always 2)

    float* ws    = (float*)d_ws;
    float* nr    = ws;
    float* ns    = nr    + ROWS * 128;
    float* recvT = ns    + ROWS * 128;
    float* sendT = recvT + ROWS * 128;
    u16* re_w1b = (u16*)(sendT + ROWS * 128);
    u16* web    = re_w1b + 16384;
    u16* pp_wb  = web    + 16384;
    u16* wrecvb = pp_wb  + 32768;
    u16* wsendb = wrecvb + 16384;
    u16* pr_w0b = wsendb + 16384;
    u16* pr_w1b = pr_w0b + 16384;
    u16* objb   = pr_w1b + 4096;
    u16* aggb   = objb + ROWS * 128;
    u16* Ebuf   = aggb + ROWS * 128;   // 8192 tiles * 8 * 64 * 4 bf16 (33.5 MB)

    k_node<<<128, 256, 0, stream>>>(attrs, states, oe_w0, oe_b0, oe_w1, oe_b1,
                                    re_w0, re_b0, rp_w, rp_b,
                                    re_w1, pp_w, pr_w0, pr_w1,
                                    re_w1b, web, pp_wb, wrecvb, wsendb, pr_w0b, pr_w1b,
                                    objb, nr, ns, recvT, sendT);
    k_edge_fused<<<2048, 256, 0, stream>>>(rel_attrs, re_w0, re_w1b, web, re_b1,
                                           rp_lnw, rp_lnb, nr, ns, recvT, sendT,
                                           Ebuf, aggb);
    k_pn0<<<128, 256, 0, stream>>>(aggb, pp_wb, pp_b, pp_lnw, pp_lnb,
                                   wrecvb, wsendb, rp_b, objb, recvT, sendT);
    k_prop_edge2<<<2048, 256, 0, stream>>>(Ebuf, rp_lnw, rp_lnb, recvT, sendT, aggb);
    k_pn1pred<<<128, 256, 0, stream>>>(aggb, pp_wb, pp_b, pp_lnw, pp_lnb, objb,
                                       pr_w0b, pr_b0, pr_w1b, pr_b1, (float*)d_out);
}

// Round 13
// 184.318 us; speedup vs baseline: 1.1310x; 1.0109x over previous
//
#include <hip/hip_runtime.h>
#include <hip/hip_bf16.h>

// CompositionalKoopmanOperators: B=32,N=64,ATTR=4,STATE=8,REL=4,GDIM=32,NF=128,pstep=2
// Round 13: r9/r12 structure; edge_fused gets __launch_bounds__(256,4) to force
// 4 waves/EU (total VGPR+AGPR ~104 <= 128 fits) -- attacks the ~26% occupancy
// that has pinned edge_fused at ~47us across r8-r12. Early-prefetch reverted
// (r12 showed it slows the kernel: oldest-in-queue vmcnt drain).

#define ROWS 2048   // B*N
typedef unsigned short u16;
typedef unsigned int u32;
typedef __attribute__((ext_vector_type(8))) short bf16x8;   // 8 bf16 = 4 VGPR
typedef __attribute__((ext_vector_type(4))) float f32x4;

__device__ __forceinline__ float bsu(u16 u) { return __uint_as_float(((u32)u) << 16); }
__device__ __forceinline__ u16 f2b(float f) {
    u32 u = __float_as_uint(f);
    u32 r = (u + 0x7fffu + ((u >> 16) & 1u)) >> 16;   // RNE
    return (u16)r;
}
__device__ __forceinline__ u32 pk2(float a, float b) {   // packed RNE cvt
    __hip_bfloat162 h = __float22bfloat162_rn(float2{a, b});
    union { __hip_bfloat162 h; u32 u; } c; c.h = h; return c.u;
}
__device__ __forceinline__ bf16x8 ldcvt8(const float* __restrict__ p) {  // 8 f32 -> bf16x8
    float4 a = *(const float4*)p;
    float4 b = *(const float4*)(p + 4);
    union { u32 u[4]; bf16x8 v; } x;
    x.u[0] = pk2(a.x, a.y); x.u[1] = pk2(a.z, a.w);
    x.u[2] = pk2(b.x, b.y); x.u[3] = pk2(b.z, b.w);
    return x.v;
}

// ---------------- k_node: prep (weight cvt) + L0 + 3 MFMA GEMMs ----------------
__global__ __launch_bounds__(256)
void k_node(const float* __restrict__ attrs, const float* __restrict__ states,
            const float* __restrict__ oe_w0, const float* __restrict__ oe_b0,
            const float* __restrict__ oe_w1, const float* __restrict__ oe_b1,
            const float* __restrict__ re_w0, const float* __restrict__ re_b0,
            const float* __restrict__ rp_w,  const float* __restrict__ rp_b,
            const float* __restrict__ re_w1, const float* __restrict__ pp_w,
            const float* __restrict__ pr_w0, const float* __restrict__ pr_w1,
            u16* __restrict__ re_w1b, u16* __restrict__ web, u16* __restrict__ pp_wb,
            u16* __restrict__ wrecvb, u16* __restrict__ wsendb,
            u16* __restrict__ pr_w0b, u16* __restrict__ pr_w1b,
            u16* __restrict__ objb, float* __restrict__ nr, float* __restrict__ ns,
            float* __restrict__ recvT, float* __restrict__ sendT)
{
    const int r0 = blockIdx.x * 16;
    const int t = threadIdx.x;
    __shared__ float xs[16][12];
    __shared__ float w0s[1536];
    __shared__ float rw0s[2560];
    __shared__ __align__(16) u16 hb[16 * 136];
    __shared__ __align__(16) u16 ob[16 * 136];

    {
        int gid = blockIdx.x * 256 + t;
        for (int i = gid; i < 118784; i += 32768) {
            int idx = i;
            if (idx < 16384) { re_w1b[idx] = f2b(re_w1[idx]); continue; }
            idx -= 16384;
            if (idx < 16384) { web[idx] = f2b(rp_w[(idx >> 7) * 384 + (idx & 127)]); continue; }
            idx -= 16384;
            if (idx < 32768) { pp_wb[idx] = f2b(pp_w[idx]); continue; }
            idx -= 32768;
            if (idx < 16384) { wrecvb[idx] = f2b(rp_w[(idx >> 7) * 384 + 128 + (idx & 127)]); continue; }
            idx -= 16384;
            if (idx < 16384) { wsendb[idx] = f2b(rp_w[(idx >> 7) * 384 + 256 + (idx & 127)]); continue; }
            idx -= 16384;
            if (idx < 16384) { pr_w0b[idx] = f2b(pr_w0[idx]); continue; }
            idx -= 16384;
            pr_w1b[idx] = f2b(pr_w1[idx]);
        }
    }

    if (t < 192) { int row = t / 12, c = t - row * 12;
        xs[row][c] = (c < 4) ? attrs[(r0 + row) * 4 + c] : states[(r0 + row) * 8 + (c - 4)]; }
    for (int i = t; i < 1536; i += 256) w0s[i] = oe_w0[i];
    for (int i = t; i < 2560; i += 256) rw0s[i] = re_w0[i];
    __syncthreads();

    for (int e = t; e < 2048; e += 256) {
        int row = e >> 7, o = e & 127;
        float h = oe_b0[o];
#pragma unroll
        for (int k = 0; k < 12; k++) h += w0s[o * 12 + k] * xs[row][k];
        hb[row * 136 + o] = f2b(fmaxf(h, 0.f));
        float s0 = 0.f, a0 = 0.f, a1 = 0.f;
#pragma unroll
        for (int k = 0; k < 8; k++) s0 += rw0s[o * 20 + 4 + k] * xs[row][4 + k];
#pragma unroll
        for (int k = 0; k < 4; k++) {
            a0 += rw0s[o * 20 + 12 + k] * xs[row][k];
            a1 += rw0s[o * 20 + 16 + k] * xs[row][k];
        }
        nr[(r0 + row) * 128 + o] = s0 + a0 + re_b0[o];
        ns[(r0 + row) * 128 + o] = a1 - s0;
    }
    __syncthreads();

    const int wave = t >> 6, lane = t & 63, tx = lane & 15, quad = lane >> 4;

    bf16x8 afr[4];
#pragma unroll
    for (int kk = 0; kk < 4; kk++) afr[kk] = *(const bf16x8*)&hb[tx * 136 + kk * 32 + quad * 8];
    f32x4 acc[2]; acc[0] = (f32x4){0.f,0.f,0.f,0.f}; acc[1] = acc[0];
#pragma unroll
    for (int ot = 0; ot < 2; ot++) {
        int o = (wave * 2 + ot) * 16 + tx;
#pragma unroll
        for (int kk = 0; kk < 4; kk++) {
            bf16x8 bfr = ldcvt8(&oe_w1[o * 128 + kk * 32 + quad * 8]);
            acc[ot] = __builtin_amdgcn_mfma_f32_16x16x32_bf16(afr[kk], bfr, acc[ot], 0, 0, 0);
        }
    }
#pragma unroll
    for (int ot = 0; ot < 2; ot++) {
        int o = (wave * 2 + ot) * 16 + tx;
        float bia = oe_b1[o];
#pragma unroll
        for (int r = 0; r < 4; r++)
            ob[(quad * 4 + r) * 136 + o] = f2b(fmaxf(acc[ot][r] + bia, 0.f));
    }
    __syncthreads();
    { int m = t >> 4, c = t & 15;
      *(uint4*)&objb[(r0 + m) * 128 + c * 8] = *(const uint4*)&ob[m * 136 + c * 8]; }

#pragma unroll
    for (int kk = 0; kk < 4; kk++) afr[kk] = *(const bf16x8*)&ob[tx * 136 + kk * 32 + quad * 8];
    f32x4 ar[2], an[2];
    ar[0] = (f32x4){0.f,0.f,0.f,0.f}; ar[1] = ar[0]; an[0] = ar[0]; an[1] = ar[0];
#pragma unroll
    for (int ot = 0; ot < 2; ot++) {
        int o = (wave * 2 + ot) * 16 + tx;
#pragma unroll
        for (int kk = 0; kk < 4; kk++) {
            bf16x8 br = ldcvt8(&rp_w[o * 384 + 128 + kk * 32 + quad * 8]);
            ar[ot] = __builtin_amdgcn_mfma_f32_16x16x32_bf16(afr[kk], br, ar[ot], 0, 0, 0);
            bf16x8 bs = ldcvt8(&rp_w[o * 384 + 256 + kk * 32 + quad * 8]);
            an[ot] = __builtin_amdgcn_mfma_f32_16x16x32_bf16(afr[kk], bs, an[ot], 0, 0, 0);
        }
    }
#pragma unroll
    for (int ot = 0; ot < 2; ot++) {
        int o = (wave * 2 + ot) * 16 + tx;
        float rb = rp_b[o];
#pragma unroll
        for (int r = 0; r < 4; r++) {
            recvT[(r0 + quad * 4 + r) * 128 + o] = ar[ot][r] + rb;
            sendT[(r0 + quad * 4 + r) * 128 + o] = an[ot][r];
        }
    }
}

// ---------------- k_edge_fused (r13): r9 body + forced 4 waves/EU ----------------
__global__ __launch_bounds__(256, 4)
void k_edge_fused(const float* __restrict__ rel_attrs,
                  const float* __restrict__ re_w0, const u16* __restrict__ re_w1b,
                  const u16* __restrict__ web, const float* __restrict__ re_b1,
                  const float* __restrict__ rp_lnw, const float* __restrict__ rp_lnb,
                  const float* __restrict__ nr, const float* __restrict__ ns,
                  const float* __restrict__ recvT, const float* __restrict__ sendT,
                  u16* __restrict__ Ebuf, u16* __restrict__ aggb)
{
    const int blkg = blockIdx.x;    // b*64 + i
    const int b = blkg >> 6;
    const int t = threadIdx.x;
    __shared__ __align__(16) u16 hsb[64 * 144];     // h0, then relE (18432 B)
    __shared__ float lnws[128], lnbs[128];
    __shared__ float redS[256], redQ[256];          // [wave][row]

    if (t < 128) { lnws[t] = rp_lnw[t]; lnbs[t] = rp_lnb[t]; }

    // ---- phase 1: h0[j][o], 8-col slice per thread, register-held weights ----
    {
        const int o0 = (t & 15) * 8;
        const int jb = t >> 4;
        float4 nr0 = *(const float4*)&nr[blkg * 128 + o0];
        float4 nr1 = *(const float4*)&nr[blkg * 128 + o0 + 4];
        float4 wreg[8];
#pragma unroll
        for (int k = 0; k < 8; k++) wreg[k] = *(const float4*)&re_w0[(o0 + k) * 20];
#pragma unroll
        for (int it = 0; it < 4; it++) {
            int j = jb + it * 16;
            float4 ra = *(const float4*)&rel_attrs[((size_t)blkg * 64 + j) * 4];
            const float* nsp = &ns[(b * 64 + j) * 128 + o0];
            float4 na = *(const float4*)nsp;
            float4 nb = *(const float4*)(nsp + 4);
            float v[8];
            v[0] = nr0.x + na.x; v[1] = nr0.y + na.y; v[2] = nr0.z + na.z; v[3] = nr0.w + na.w;
            v[4] = nr1.x + nb.x; v[5] = nr1.y + nb.y; v[6] = nr1.z + nb.z; v[7] = nr1.w + nb.w;
#pragma unroll
            for (int k = 0; k < 8; k++) {
                v[k] += wreg[k].x * ra.x + wreg[k].y * ra.y + wreg[k].z * ra.z + wreg[k].w * ra.w;
                v[k] = fmaxf(v[k], 0.f);
            }
            union { u32 u[4]; uint4 q; } p;
            p.u[0] = pk2(v[0], v[1]); p.u[1] = pk2(v[2], v[3]);
            p.u[2] = pk2(v[4], v[5]); p.u[3] = pk2(v[6], v[7]);
            *(uint4*)&hsb[j * 144 + o0] = p.q;
        }
    }

    const int w = t >> 6, lane = t & 63, tx = lane & 15, quad = lane >> 4;
    const int ob = w * 32;              // this wave's output-column base

    // B1 fragments (bf16, prepped): registers for whole GEMM
    bf16x8 b1[2][4];
#pragma unroll
    for (int ot = 0; ot < 2; ot++)
#pragma unroll
        for (int kk = 0; kk < 4; kk++)
            b1[ot][kk] = *(const bf16x8*)&re_w1b[(ob + ot * 16 + tx) * 128 + kk * 32 + quad * 8];
    __syncthreads();

    // GEMM1
    f32x4 acc[4][2];
#pragma unroll
    for (int jt = 0; jt < 4; jt++) { acc[jt][0] = (f32x4){0.f,0.f,0.f,0.f}; acc[jt][1] = acc[jt][0]; }
#pragma unroll
    for (int jt = 0; jt < 4; jt++) {
        bf16x8 afr[4];
#pragma unroll
        for (int kk = 0; kk < 4; kk++)
            afr[kk] = *(const bf16x8*)&hsb[(jt * 16 + tx) * 144 + kk * 32 + quad * 8];
#pragma unroll
        for (int ot = 0; ot < 2; ot++)
#pragma unroll
            for (int kk = 0; kk < 4; kk++)
                acc[jt][ot] = __builtin_amdgcn_mfma_f32_16x16x32_bf16(afr[kk], b1[ot][kk], acc[jt][ot], 0, 0, 0);
    }
    __syncthreads();

    // epilogue1: relu(acc + bias) -> relE back into hsb
    {
        float bia0 = re_b1[ob + tx], bia1 = re_b1[ob + 16 + tx];
#pragma unroll
        for (int jt = 0; jt < 4; jt++)
#pragma unroll
            for (int r = 0; r < 4; r++) {
                int j = jt * 16 + quad * 4 + r;
                hsb[j * 144 + ob + tx]      = f2b(fmaxf(acc[jt][0][r] + bia0, 0.f));
                hsb[j * 144 + ob + 16 + tx] = f2b(fmaxf(acc[jt][1][r] + bia1, 0.f));
            }
    }
    bf16x8 b2[2][4];
#pragma unroll
    for (int ot = 0; ot < 2; ot++)
#pragma unroll
        for (int kk = 0; kk < 4; kk++)
            b2[ot][kk] = *(const bf16x8*)&web[(ob + ot * 16 + tx) * 128 + kk * 32 + quad * 8];
    __syncthreads();

    // GEMM2
    f32x4 acc2[4][2];
#pragma unroll
    for (int jt = 0; jt < 4; jt++) { acc2[jt][0] = (f32x4){0.f,0.f,0.f,0.f}; acc2[jt][1] = acc2[jt][0]; }
#pragma unroll
    for (int jt = 0; jt < 4; jt++) {
        bf16x8 afr[4];
#pragma unroll
        for (int kk = 0; kk < 4; kk++)
            afr[kk] = *(const bf16x8*)&hsb[(jt * 16 + tx) * 144 + kk * 32 + quad * 8];
#pragma unroll
        for (int ot = 0; ot < 2; ot++)
#pragma unroll
            for (int kk = 0; kk < 4; kk++)
                acc2[jt][ot] = __builtin_amdgcn_mfma_f32_16x16x32_bf16(afr[kk], b2[ot][kk], acc2[jt][ot], 0, 0, 0);
    }

    // store E (pre recv/send), packed cvt, prop_edge2-compatible fragment order
#pragma unroll
    for (int jt = 0; jt < 4; jt++)
#pragma unroll
        for (int ot = 0; ot < 2; ot++) {
            uint2 ev;
            ev.x = pk2(acc2[jt][ot][0], acc2[jt][ot][1]);
            ev.y = pk2(acc2[jt][ot][2], acc2[jt][ot][3]);
            *(uint2*)(Ebuf + ((size_t)((blkg * 4 + jt) * 8 + (2 * w + ot)) * 64 + lane) * 4) = ev;
        }

    // y = E + recvT[i][o] + sendT[j][o]
    {
        float rv0 = recvT[blkg * 128 + ob + tx];
        float rv1 = recvT[blkg * 128 + ob + 16 + tx];
#pragma unroll
        for (int jt = 0; jt < 4; jt++)
#pragma unroll
            for (int r = 0; r < 4; r++) {
                int j = b * 64 + jt * 16 + quad * 4 + r;
                acc2[jt][0][r] += rv0 + sendT[j * 128 + ob + tx];
                acc2[jt][1][r] += rv1 + sendT[j * 128 + ob + 16 + tx];
            }
    }

    // LN row partials -> LDS
#pragma unroll
    for (int jt = 0; jt < 4; jt++) {
        float s4[4], q4[4];
#pragma unroll
        for (int r = 0; r < 4; r++) {
            float a0 = acc2[jt][0][r], a1 = acc2[jt][1][r];
            s4[r] = a0 + a1; q4[r] = a0 * a0 + a1 * a1;
        }
#pragma unroll
        for (int m = 1; m < 16; m <<= 1)
#pragma unroll
            for (int r = 0; r < 4; r++) {
                s4[r] += __shfl_xor(s4[r], m, 64);
                q4[r] += __shfl_xor(q4[r], m, 64);
            }
        if (tx == 0)
#pragma unroll
            for (int r = 0; r < 4; r++) {
                redS[w * 64 + jt * 16 + quad * 4 + r] = s4[r];
                redQ[w * 64 + jt * 16 + quad * 4 + r] = q4[r];
            }
    }
    __syncthreads();

    // normalize + relu + per-col agg
    {
        float lw0 = lnws[ob + tx], lb0 = lnbs[ob + tx];
        float lw1 = lnws[ob + 16 + tx], lb1 = lnbs[ob + 16 + tx];
        float ag0 = 0.f, ag1 = 0.f;
#pragma unroll
        for (int jt = 0; jt < 4; jt++)
#pragma unroll
            for (int r = 0; r < 4; r++) {
                int row = jt * 16 + quad * 4 + r;
                float ss = redS[row] + redS[64 + row] + redS[128 + row] + redS[192 + row];
                float qq = redQ[row] + redQ[64 + row] + redQ[128 + row] + redQ[192 + row];
                float mu = ss * (1.f / 128.f);
                float rsd = rsqrtf(qq * (1.f / 128.f) - mu * mu + 1e-5f);
                float z0 = (acc2[jt][0][r] - mu) * rsd * lw0 + lb0;
                float z1 = (acc2[jt][1][r] - mu) * rsd * lw1 + lb1;
                ag0 += fmaxf(z0, 0.f);
                ag1 += fmaxf(z1, 0.f);
            }
        ag0 += __shfl_xor(ag0, 16, 64); ag0 += __shfl_xor(ag0, 32, 64);
        ag1 += __shfl_xor(ag1, 16, 64); ag1 += __shfl_xor(ag1, 32, 64);
        if (quad == 0) {
            aggb[blkg * 128 + ob + tx]      = f2b(ag0);
            aggb[blkg * 128 + ob + 16 + tx] = f2b(ag1);
        }
    }
}

// ---------------- k_prop_edge2: step-1, no GEMM ----------------
__global__ __launch_bounds__(256)
void k_prop_edge2(const u16* __restrict__ Ebuf,
                  const float* __restrict__ rp_lnw, const float* __restrict__ rp_lnb,
                  const float* __restrict__ recvT, const float* __restrict__ sendT,
                  u16* __restrict__ aggb)
{
    const int blk = blockIdx.x;   // b*64 + i
    const int b = blk >> 6;
    const int t = threadIdx.x;
    __shared__ float scr[16 * 132];
    __shared__ float lnws[128], lnbs[128];
    if (t < 128) { lnws[t] = rp_lnw[t]; lnbs[t] = rp_lnb[t]; }
    __syncthreads();

    const int wave = t >> 6, lane = t & 63, tx = lane & 15, quad = lane >> 4;
    const int tid = blk * 4 + wave;
    const int jrow = wave * 16 + quad * 4;

    float y[8][4];
#pragma unroll
    for (int oo = 0; oo < 8; oo++) {
        uint2 ev = *(const uint2*)(Ebuf + ((size_t)(tid * 8 + oo) * 64 + lane) * 4);
        const int o = oo * 16 + tx;
        float rv = recvT[blk * 128 + o];
        float e0 = bsu((u16)(ev.x & 0xffff)), e1 = bsu((u16)(ev.x >> 16));
        float e2 = bsu((u16)(ev.y & 0xffff)), e3 = bsu((u16)(ev.y >> 16));
        y[oo][0] = e0 + rv + sendT[(b * 64 + jrow + 0) * 128 + o];
        y[oo][1] = e1 + rv + sendT[(b * 64 + jrow + 1) * 128 + o];
        y[oo][2] = e2 + rv + sendT[(b * 64 + jrow + 2) * 128 + o];
        y[oo][3] = e3 + rv + sendT[(b * 64 + jrow + 3) * 128 + o];
    }
    float s[4], q[4];
#pragma unroll
    for (int r = 0; r < 4; r++) {
        s[r] = 0.f; q[r] = 0.f;
#pragma unroll
        for (int oo = 0; oo < 8; oo++) { s[r] += y[oo][r]; q[r] += y[oo][r] * y[oo][r]; }
    }
#pragma unroll
    for (int m = 1; m < 16; m <<= 1) {
#pragma unroll
        for (int r = 0; r < 4; r++) {
            s[r] += __shfl_xor(s[r], m, 64);
            q[r] += __shfl_xor(q[r], m, 64);
        }
    }
    float mu[4], rs[4];
#pragma unroll
    for (int r = 0; r < 4; r++) {
        mu[r] = s[r] * (1.f / 128.f);
        rs[r] = rsqrtf(q[r] * (1.f / 128.f) - mu[r] * mu[r] + 1e-5f);
    }
    float pa[8];
#pragma unroll
    for (int oo = 0; oo < 8; oo++) {
        const int o = oo * 16 + tx;
        float lw = lnws[o], lb = lnbs[o];
        float p = 0.f;
#pragma unroll
        for (int r = 0; r < 4; r++) {
            float z = (y[oo][r] - mu[r]) * rs[r] * lw + lb;
            p += fmaxf(z, 0.f);
        }
        pa[oo] = p;
    }
    const int grp = wave * 4 + quad;
#pragma unroll
    for (int oo = 0; oo < 8; oo++) scr[grp * 132 + oo * 16 + tx] = pa[oo];
    __syncthreads();
    if (t < 128) {
        float sum = 0.f;
#pragma unroll
        for (int gg = 0; gg < 16; gg++) sum += scr[gg * 132 + t];
        aggb[blk * 128 + t] = f2b(sum);
    }
}

// ---------------- k_pn0: prop step 0 node (pp + LN + relu + next recv/send terms) ----
__global__ __launch_bounds__(256)
void k_pn0(const u16* __restrict__ aggb,
           const u16* __restrict__ pp_wb, const float* __restrict__ pp_b,
           const float* __restrict__ pp_lnw, const float* __restrict__ pp_lnb,
           const u16* __restrict__ wrecvb, const u16* __restrict__ wsendb,
           const float* __restrict__ rp_b,
           u16* __restrict__ objb, float* __restrict__ recvT, float* __restrict__ sendT)
{
    const int r0 = blockIdx.x * 16;
    const int t = threadIdx.x;
    __shared__ __align__(16) u16 ab[16 * 264];
    __shared__ __align__(16) u16 ob[16 * 136];
    __shared__ float redS[64], redQ[64];

    for (int i = t; i < 512; i += 256) {
        int m = i >> 5, c = i & 31;
        uint4 v = (c < 16) ? *(const uint4*)&objb[(r0 + m) * 128 + (c & 15) * 8]
                           : *(const uint4*)&aggb[(r0 + m) * 128 + (c - 16) * 8];
        *(uint4*)&ab[m * 264 + c * 8] = v;
    }
    __syncthreads();

    const int wave = t >> 6, lane = t & 63, tx = lane & 15, quad = lane >> 4;
    bf16x8 afr[8];
#pragma unroll
    for (int kk = 0; kk < 8; kk++) afr[kk] = *(const bf16x8*)&ab[tx * 264 + kk * 32 + quad * 8];
    f32x4 acc[2]; acc[0] = (f32x4){0.f,0.f,0.f,0.f}; acc[1] = acc[0];
#pragma unroll
    for (int ot = 0; ot < 2; ot++) {
        int o = (wave * 2 + ot) * 16 + tx;
#pragma unroll
        for (int kk = 0; kk < 8; kk++) {
            bf16x8 bfr = *(const bf16x8*)&pp_wb[o * 256 + kk * 32 + quad * 8];
            acc[ot] = __builtin_amdgcn_mfma_f32_16x16x32_bf16(afr[kk], bfr, acc[ot], 0, 0, 0);
        }
    }
#pragma unroll
    for (int ot = 0; ot < 2; ot++) {
        float bia = pp_b[(wave * 2 + ot) * 16 + tx];
#pragma unroll
        for (int r = 0; r < 4; r++) acc[ot][r] += bia;
    }

    float s[4], q[4];
#pragma unroll
    for (int r = 0; r < 4; r++) {
        s[r] = acc[0][r] + acc[1][r];
        q[r] = acc[0][r] * acc[0][r] + acc[1][r] * acc[1][r];
    }
#pragma unroll
    for (int m = 1; m < 16; m <<= 1) {
#pragma unroll
        for (int r = 0; r < 4; r++) {
            s[r] += __shfl_xor(s[r], m, 64);
            q[r] += __shfl_xor(q[r], m, 64);
        }
    }
    if (tx == 0) {
#pragma unroll
        for (int r = 0; r < 4; r++) {
            redS[wave * 16 + quad * 4 + r] = s[r];
            redQ[wave * 16 + quad * 4 + r] = q[r];
        }
    }
    __syncthreads();
    float mu[4], rs[4];
#pragma unroll
    for (int r = 0; r < 4; r++) {
        int m = quad * 4 + r;
        float ss = redS[m] + redS[16 + m] + redS[32 + m] + redS[48 + m];
        float qq = redQ[m] + redQ[16 + m] + redQ[32 + m] + redQ[48 + m];
        mu[r] = ss * (1.f / 128.f);
        rs[r] = rsqrtf(qq * (1.f / 128.f) - mu[r] * mu[r] + 1e-5f);
    }
#pragma unroll
    for (int ot = 0; ot < 2; ot++) {
        int o = (wave * 2 + ot) * 16 + tx;
        float lw = pp_lnw[o], lb = pp_lnb[o];
#pragma unroll
        for (int r = 0; r < 4; r++) {
            float z = (acc[ot][r] - mu[r]) * rs[r] * lw + lb;
            ob[(quad * 4 + r) * 136 + o] = f2b(fmaxf(z, 0.f));
        }
    }
    __syncthreads();
    { int m = t >> 4, c = t & 15;
      *(uint4*)&objb[(r0 + m) * 128 + c * 8] = *(const uint4*)&ob[m * 136 + c * 8]; }

    bf16x8 af2[4];
#pragma unroll
    for (int kk = 0; kk < 4; kk++) af2[kk] = *(const bf16x8*)&ob[tx * 136 + kk * 32 + quad * 8];
    f32x4 ar[2], an[2];
    ar[0] = (f32x4){0.f,0.f,0.f,0.f}; ar[1] = ar[0]; an[0] = ar[0]; an[1] = ar[0];
#pragma unroll
    for (int ot = 0; ot < 2; ot++) {
        int o = (wave * 2 + ot) * 16 + tx;
#pragma unroll
        for (int kk = 0; kk < 4; kk++) {
            bf16x8 br = *(const bf16x8*)&wrecvb[o * 128 + kk * 32 + quad * 8];
            ar[ot] = __builtin_amdgcn_mfma_f32_16x16x32_bf16(af2[kk], br, ar[ot], 0, 0, 0);
            bf16x8 bs = *(const bf16x8*)&wsendb[o * 128 + kk * 32 + quad * 8];
            an[ot] = __builtin_amdgcn_mfma_f32_16x16x32_bf16(af2[kk], bs, an[ot], 0, 0, 0);
        }
    }
#pragma unroll
    for (int ot = 0; ot < 2; ot++) {
        int o = (wave * 2 + ot) * 16 + tx;
        float rb = rp_b[o];
#pragma unroll
        for (int r = 0; r < 4; r++) {
            recvT[(r0 + quad * 4 + r) * 128 + o] = ar[ot][r] + rb;
            sendT[(r0 + quad * 4 + r) * 128 + o] = an[ot][r];
        }
    }
}

// ---------------- k_pn1pred: prop step 1 node + predictor + tanh, fused ----------------
__global__ __launch_bounds__(256)
void k_pn1pred(const u16* __restrict__ aggb,
               const u16* __restrict__ pp_wb, const float* __restrict__ pp_b,
               const float* __restrict__ pp_lnw, const float* __restrict__ pp_lnb,
               const u16* __restrict__ objb,
               const u16* __restrict__ pr_w0b, const float* __restrict__ pr_b0,
               const u16* __restrict__ pr_w1b, const float* __restrict__ pr_b1,
               float* __restrict__ out)
{
    const int r0 = blockIdx.x * 16;
    const int t = threadIdx.x;
    __shared__ __align__(16) u16 ab[16 * 264];
    __shared__ __align__(16) u16 ob[16 * 136];
    __shared__ __align__(16) u16 hb2[16 * 136];
    __shared__ float redS[64], redQ[64];

    for (int i = t; i < 512; i += 256) {
        int m = i >> 5, c = i & 31;
        uint4 v = (c < 16) ? *(const uint4*)&objb[(r0 + m) * 128 + (c & 15) * 8]
                           : *(const uint4*)&aggb[(r0 + m) * 128 + (c - 16) * 8];
        *(uint4*)&ab[m * 264 + c * 8] = v;
    }
    __syncthreads();

    const int wave = t >> 6, lane = t & 63, tx = lane & 15, quad = lane >> 4;
    bf16x8 afr[8];
#pragma unroll
    for (int kk = 0; kk < 8; kk++) afr[kk] = *(const bf16x8*)&ab[tx * 264 + kk * 32 + quad * 8];
    f32x4 acc[2]; acc[0] = (f32x4){0.f,0.f,0.f,0.f}; acc[1] = acc[0];
#pragma unroll
    for (int ot = 0; ot < 2; ot++) {
        int o = (wave * 2 + ot) * 16 + tx;
#pragma unroll
        for (int kk = 0; kk < 8; kk++) {
            bf16x8 bfr = *(const bf16x8*)&pp_wb[o * 256 + kk * 32 + quad * 8];
            acc[ot] = __builtin_amdgcn_mfma_f32_16x16x32_bf16(afr[kk], bfr, acc[ot], 0, 0, 0);
        }
    }
#pragma unroll
    for (int ot = 0; ot < 2; ot++) {
        float bia = pp_b[(wave * 2 + ot) * 16 + tx];
#pragma unroll
        for (int r = 0; r < 4; r++) acc[ot][r] += bia;
    }

    float s[4], q[4];
#pragma unroll
    for (int r = 0; r < 4; r++) {
        s[r] = acc[0][r] + acc[1][r];
        q[r] = acc[0][r] * acc[0][r] + acc[1][r] * acc[1][r];
    }
#pragma unroll
    for (int m = 1; m < 16; m <<= 1) {
#pragma unroll
        for (int r = 0; r < 4; r++) {
            s[r] += __shfl_xor(s[r], m, 64);
            q[r] += __shfl_xor(q[r], m, 64);
        }
    }
    if (tx == 0) {
#pragma unroll
        for (int r = 0; r < 4; r++) {
            redS[wave * 16 + quad * 4 + r] = s[r];
            redQ[wave * 16 + quad * 4 + r] = q[r];
        }
    }
    __syncthreads();
    float mu[4], rs[4];
#pragma unroll
    for (int r = 0; r < 4; r++) {
        int m = quad * 4 + r;
        float ss = redS[m] + redS[16 + m] + redS[32 + m] + redS[48 + m];
        float qq = redQ[m] + redQ[16 + m] + redQ[32 + m] + redQ[48 + m];
        mu[r] = ss * (1.f / 128.f);
        rs[r] = rsqrtf(qq * (1.f / 128.f) - mu[r] * mu[r] + 1e-5f);
    }
#pragma unroll
    for (int ot = 0; ot < 2; ot++) {
        int o = (wave * 2 + ot) * 16 + tx;
        float lw = pp_lnw[o], lb = pp_lnb[o];
#pragma unroll
        for (int r = 0; r < 4; r++) {
            float z = (acc[ot][r] - mu[r]) * rs[r] * lw + lb;
            ob[(quad * 4 + r) * 136 + o] = f2b(fmaxf(z, 0.f));
        }
    }
    __syncthreads();

    // ---- predictor layer 0: h = relu(obj @ pr_w0^T + b0) ----
    bf16x8 af2[4];
#pragma unroll
    for (int kk = 0; kk < 4; kk++) af2[kk] = *(const bf16x8*)&ob[tx * 136 + kk * 32 + quad * 8];
    f32x4 ah[2]; ah[0] = (f32x4){0.f,0.f,0.f,0.f}; ah[1] = ah[0];
#pragma unroll
    for (int ot = 0; ot < 2; ot++) {
        int o = (wave * 2 + ot) * 16 + tx;
#pragma unroll
        for (int kk = 0; kk < 4; kk++) {
            bf16x8 bfr = *(const bf16x8*)&pr_w0b[o * 128 + kk * 32 + quad * 8];
            ah[ot] = __builtin_amdgcn_mfma_f32_16x16x32_bf16(af2[kk], bfr, ah[ot], 0, 0, 0);
        }
    }
#pragma unroll
    for (int ot = 0; ot < 2; ot++) {
        int o = (wave * 2 + ot) * 16 + tx;
        float bia = pr_b0[o];
#pragma unroll
        for (int r = 0; r < 4; r++)
            hb2[(quad * 4 + r) * 136 + o] = f2b(fmaxf(ah[ot][r] + bia, 0.f));
    }
    __syncthreads();

    // ---- predictor layer 1 (GDIM=32) + tanh ----
    if (wave < 2) {
        bf16x8 af3[4];
#pragma unroll
        for (int kk = 0; kk < 4; kk++) af3[kk] = *(const bf16x8*)&hb2[tx * 136 + kk * 32 + quad * 8];
        f32x4 a2 = (f32x4){0.f,0.f,0.f,0.f};
        int o = wave * 16 + tx;
#pragma unroll
        for (int kk = 0; kk < 4; kk++) {
            bf16x8 bfr = *(const bf16x8*)&pr_w1b[o * 128 + kk * 32 + quad * 8];
            a2 = __builtin_amdgcn_mfma_f32_16x16x32_bf16(af3[kk], bfr, a2, 0, 0, 0);
        }
        float bia = pr_b1[o];
#pragma unroll
        for (int r = 0; r < 4; r++)
            out[(r0 + quad * 4 + r) * 32 + o] = tanhf(a2[r] + bia);
    }
}

extern "C" void kernel_launch(void* const* d_in, const int* in_sizes, int n_in,
                              void* d_out, int out_size, void* d_ws, size_t ws_size,
                              hipStream_t stream)
{
    const float* attrs    = (const float*)d_in[0];
    const float* states   = (const float*)d_in[1];
    const float* rel_attrs= (const float*)d_in[3];
    const float* oe_w0 = (const float*)d_in[4];
    const float* oe_b0 = (const float*)d_in[5];
    const float* oe_w1 = (const float*)d_in[6];
    const float* oe_b1 = (const float*)d_in[7];
    const float* re_w0 = (const float*)d_in[8];
    const float* re_b0 = (const float*)d_in[9];
    const float* re_w1 = (const float*)d_in[10];
    const float* re_b1 = (const float*)d_in[11];
    const float* rp_w  = (const float*)d_in[12];
    const float* rp_b  = (const float*)d_in[13];
    const float* rp_lnw= (const float*)d_in[14];
    const float* rp_lnb= (const float*)d_in[15];
    const float* pp_w  = (const float*)d_in[16];
    const float* pp_b  = (const float*)d_in[17];
    const float* pp_lnw= (const float*)d_in[18];
    const float* pp_lnb= (const float*)d_in[19];
    const float* pr_w0 = (const float*)d_in[20];
    const float* pr_b0 = (const float*)d_in[21];
    const float* pr_w1 = (const float*)d_in[22];
    const float* pr_b1 = (const float*)d_in[23];
    // d_in[24] = pstep (always 2)

    float* ws    = (float*)d_ws;
    float* nr    = ws;
    float* ns    = nr    + ROWS * 128;
    float* recvT = ns    + ROWS * 128;
    float* sendT = recvT + ROWS * 128;
    u16* re_w1b = (u16*)(sendT + ROWS * 128);
    u16* web    = re_w1b + 16384;
    u16* pp_wb  = web    + 16384;
    u16* wrecvb = pp_wb  + 32768;
    u16* wsendb = wrecvb + 16384;
    u16* pr_w0b = wsendb + 16384;
    u16* pr_w1b = pr_w0b + 16384;
    u16* objb   = pr_w1b + 4096;
    u16* aggb   = objb + ROWS * 128;
    u16* Ebuf   = aggb + ROWS * 128;   // 8192 tiles * 8 * 64 * 4 bf16 (33.5 MB)

    k_node<<<128, 256, 0, stream>>>(attrs, states, oe_w0, oe_b0, oe_w1, oe_b1,
                                    re_w0, re_b0, rp_w, rp_b,
                                    re_w1, pp_w, pr_w0, pr_w1,
                                    re_w1b, web, pp_wb, wrecvb, wsendb, pr_w0b, pr_w1b,
                                    objb, nr, ns, recvT, sendT);
    k_edge_fused<<<2048, 256, 0, stream>>>(rel_attrs, re_w0, re_w1b, web, re_b1,
                                           rp_lnw, rp_lnb, nr, ns, recvT, sendT,
                                           Ebuf, aggb);
    k_pn0<<<128, 256, 0, stream>>>(aggb, pp_wb, pp_b, pp_lnw, pp_lnb,
                                   wrecvb, wsendb, rp_b, objb, recvT, sendT);
    k_prop_edge2<<<2048, 256, 0, stream>>>(Ebuf, rp_lnw, rp_lnb, recvT, sendT, aggb);
    k_pn1pred<<<128, 256, 0, stream>>>(aggb, pp_wb, pp_b, pp_lnw, pp_lnb, objb,
                                       pr_w0b, pr_b0, pr_w1b, pr_b1, (float*)d_out);
}